// Round 1
// baseline (2678.246 us; speedup 1.0000x reference)
//
#include <hip/hip_runtime.h>
#include <math.h>

#define BATCH   2
#define CDIM    64
#define DSTATE  8
#define DINNER  128
#define DTRANK  4
#define CDBL    20       // DTRANK + 2*DSTATE
#define HDIM    128
#define WDIM    128
#define LTOT    16384    // HDIM*WDIM
#define NHID    192      // HIDDEN
#define NC      256      // scan chunks
#define CHUNKL  64       // LTOT / NC

// ---- workspace offsets (floats) ----
static const size_t OFF_XF    = 0;            // 2*64*16384   = 2097152
static const size_t OFF_Z     = 2097152;      // (B,L,128)    = 4194304
static const size_t OFF_XIN   = 6291456;      // (B,128,L)    = 4194304
static const size_t OFF_XS    = 10485760;     // (B,128,L)    = 4194304
static const size_t OFF_DELTA = 14680064;     // (B,128,L)    = 4194304
static const size_t OFF_XDBL0 = 18874368;     // (B,20,L)     = 655360
static const size_t OFF_XDBL1 = 19529728;     // (B,20,L)     = 655360
static const size_t OFF_PS    = 20185088;     // 2*128*256*16 = 1048576
static const size_t OFF_HINIT = 21233664;     // 2*128*256*8  = 524288
static const size_t OFF_Y     = OFF_XIN;      // reuse xin
// EDFFN phase (reuses dead SS2D buffers)
static const size_t OFF_H2    = 0;            // (B,384,L)    = 12582912
static const size_t OFF_G     = 12582912;     // (B,192,L)    = 6291456
static const size_t OFF_Y2    = 18874368;     // (B,64,L)     = 2097152
static const size_t OFF_KK    = 21757952;     // 64*8*8       = 4096
// total floats = 21762048  (~87 MB)

__device__ __forceinline__ float gelu_exact(float x){
    return x * 0.5f * (1.0f + erff(x * 0.70710678118654752f));
}
__device__ __forceinline__ float softplus_f(float x){
    return (x > 20.0f) ? x : log1pf(expf(x));
}

// ---------------- K1: flip H,W ----------------
__global__ __launch_bounds__(256) void k_flip(const float* __restrict__ x, float* __restrict__ xf){
    int idx = blockIdx.x*256 + threadIdx.x;
    if (idx >= BATCH*CDIM*LTOT) return;
    int l = idx & (LTOT-1); int bc = idx >> 14;
    int h = l >> 7, w = l & (WDIM-1);
    xf[idx] = x[(size_t)bc*LTOT + (HDIM-1-h)*WDIM + (WDIM-1-w)];
}

// ------------- K2: wb_ln(norm1) + in_proj (wave per position) -------------
__global__ __launch_bounds__(256) void k_ln_inproj(const float* __restrict__ xf,
        const float* __restrict__ nw, const float* __restrict__ nb,
        const float* __restrict__ Wp, float* __restrict__ xin, float* __restrict__ z){
    int wave = (blockIdx.x*256 + threadIdx.x) >> 6;
    int lane = threadIdx.x & 63;
    if (wave >= BATCH*LTOT) return;
    int b = wave >> 14, l = wave & (LTOT-1);
    float v = xf[((size_t)b*CDIM + lane)*LTOT + l];
    float s = v*v;
    #pragma unroll
    for (int off=32; off; off>>=1) s += __shfl_xor(s, off);
    float r  = rsqrtf(s * (1.0f/CDIM) + 1e-6f);
    float xn = v * r * nw[lane] + nb[lane];
    float a0=0.f,a1=0.f,a2=0.f,a3=0.f;
    for (int c=0;c<CDIM;c++){
        float xc = __shfl(xn, c);
        a0 += xc * Wp[(lane      )*CDIM + c];
        a1 += xc * Wp[(lane + 64 )*CDIM + c];
        a2 += xc * Wp[(lane + 128)*CDIM + c];
        a3 += xc * Wp[(lane + 192)*CDIM + c];
    }
    xin[((size_t)b*DINNER + lane     )*LTOT + l] = a0;
    xin[((size_t)b*DINNER + lane + 64)*LTOT + l] = a1;
    z[((size_t)b*LTOT + l)*DINNER + lane     ] = a2;
    z[((size_t)b*LTOT + l)*DINNER + lane + 64] = a3;
}

// ------------- K3: depthwise conv2d 3x3 + gelu -------------
__global__ __launch_bounds__(256) void k_dwconv2d_gelu(const float* __restrict__ xin,
        const float* __restrict__ cw, const float* __restrict__ cb, float* __restrict__ xs){
    int idx = blockIdx.x*256 + threadIdx.x;
    if (idx >= BATCH*DINNER*LTOT) return;
    int l = idx & (LTOT-1); int bd = idx >> 14; int d = bd & (DINNER-1);
    int h = l >> 7, w = l & (WDIM-1);
    const float* base = xin + (size_t)bd*LTOT;
    float acc = cb[d];
    #pragma unroll
    for (int dh=-1; dh<=1; dh++){
        int hh = h+dh; if (hh<0||hh>=HDIM) continue;
        #pragma unroll
        for (int dw=-1; dw<=1; dw++){
            int ww = w+dw; if (ww<0||ww>=WDIM) continue;
            acc += base[hh*WDIM+ww] * cw[d*9 + (dh+1)*3 + (dw+1)];
        }
    }
    xs[idx] = gelu_exact(acc);
}

// ------------- K4: x_proj (128 -> 20) -------------
__global__ __launch_bounds__(256) void k_xproj(const float* __restrict__ xs,
        const float* __restrict__ Wx, float* __restrict__ xdbl_pre){
    int idx = blockIdx.x*256 + threadIdx.x;
    if (idx >= BATCH*LTOT) return;
    int b = idx >> 14, l = idx & (LTOT-1);
    float acc[CDBL];
    #pragma unroll
    for (int r=0;r<CDBL;r++) acc[r]=0.f;
    for (int d=0; d<DINNER; d++){
        float v = xs[((size_t)b*DINNER+d)*LTOT + l];
        #pragma unroll
        for (int r=0;r<CDBL;r++) acc[r] += v * Wx[r*DINNER+d];
    }
    #pragma unroll
    for (int r=0;r<CDBL;r++) xdbl_pre[((size_t)b*CDBL+r)*LTOT + l] = acc[r];
}

// ------------- K5: depthwise conv1d k=7 pad=3 + bias -------------
__global__ __launch_bounds__(256) void k_dwconv1d(const float* __restrict__ xp,
        const float* __restrict__ cw, const float* __restrict__ cb, float* __restrict__ xdbl){
    int idx = blockIdx.x*256 + threadIdx.x;
    if (idx >= BATCH*CDBL*LTOT) return;
    int l = idx & (LTOT-1); int br = idx >> 14; int r = br % CDBL;
    const float* base = xp + (size_t)br*LTOT;
    float acc = cb[r];
    #pragma unroll
    for (int k=0;k<7;k++){
        int t = l + k - 3;
        if (t>=0 && t<LTOT) acc += base[t]*cw[r*7+k];
    }
    xdbl[idx] = acc;
}

// ------------- K6: dts -> delta = softplus(dt_proj + bias) -------------
__global__ __launch_bounds__(256) void k_delta(const float* __restrict__ xdbl,
        const float* __restrict__ dtw, const float* __restrict__ dtb, float* __restrict__ delta){
    int idx = blockIdx.x*256 + threadIdx.x;
    if (idx >= BATCH*DINNER*LTOT) return;
    int l = idx & (LTOT-1); int bd = idx >> 14; int d = bd & (DINNER-1); int b = bd >> 7;
    const float* xb = xdbl + (size_t)b*CDBL*LTOT;
    float s = dtb[d];
    #pragma unroll
    for (int r=0;r<DTRANK;r++) s += xb[(size_t)r*LTOT + l] * dtw[d*DTRANK+r];
    delta[idx] = softplus_f(s);
}

// ------------- K7: scan pass1 (per-chunk P,S) -------------
__global__ __launch_bounds__(256) void k_scan1(const float* __restrict__ delta,
        const float* __restrict__ xs, const float* __restrict__ xdbl,
        const float* __restrict__ A_logs, float* __restrict__ PS){
    int idx = blockIdx.x*256 + threadIdx.x;
    if (idx >= BATCH*DINNER*NC) return;
    int c = idx & (NC-1); int bd = idx >> 8; int d = bd & (DINNER-1); int b = bd >> 7;
    float A[DSTATE];
    #pragma unroll
    for (int n=0;n<DSTATE;n++) A[n] = -expf(A_logs[d*DSTATE+n]);
    const float* dl = delta + (size_t)bd*LTOT + c*CHUNKL;
    const float* xv = xs    + (size_t)bd*LTOT + c*CHUNKL;
    const float* Bv = xdbl  + ((size_t)b*CDBL + DTRANK)*LTOT + c*CHUNKL;
    float h[DSTATE] = {0,0,0,0,0,0,0,0};
    float sdt = 0.f;
    for (int t=0;t<CHUNKL;t++){
        float dt = dl[t];
        float dx = dt * xv[t];
        sdt += dt;
        #pragma unroll
        for (int n=0;n<DSTATE;n++){
            float a = expf(dt*A[n]);
            h[n] = a*h[n] + dx*Bv[(size_t)n*LTOT + t];
        }
    }
    float* ps = PS + (size_t)idx*16;
    #pragma unroll
    for (int n=0;n<DSTATE;n++){ ps[n] = expf(sdt*A[n]); ps[8+n] = h[n]; }
}

// ------------- K8: cross-chunk scan -------------
__global__ __launch_bounds__(256) void k_scan2(const float* __restrict__ PS, float* __restrict__ Hinit){
    int idx = blockIdx.x*256 + threadIdx.x;
    if (idx >= BATCH*DINNER*DSTATE) return;
    int n = idx & (DSTATE-1); int bd = idx >> 3;
    float h = 0.f;
    for (int c=0;c<NC;c++){
        Hinit[((size_t)bd*NC + c)*DSTATE + n] = h;
        const float* ps = PS + ((size_t)bd*NC + c)*16;
        h = ps[n]*h + ps[8+n];
    }
}

// ------------- K9: scan pass2 (replay + y) -------------
__global__ __launch_bounds__(256) void k_scan3(const float* __restrict__ delta,
        const float* __restrict__ xs, const float* __restrict__ xdbl,
        const float* __restrict__ A_logs, const float* __restrict__ Ds,
        const float* __restrict__ Hinit, float* __restrict__ y){
    int idx = blockIdx.x*256 + threadIdx.x;
    if (idx >= BATCH*DINNER*NC) return;
    int c = idx & (NC-1); int bd = idx >> 8; int d = bd & (DINNER-1); int b = bd >> 7;
    float A[DSTATE];
    #pragma unroll
    for (int n=0;n<DSTATE;n++) A[n] = -expf(A_logs[d*DSTATE+n]);
    const float* dl = delta + (size_t)bd*LTOT + c*CHUNKL;
    const float* xv = xs    + (size_t)bd*LTOT + c*CHUNKL;
    const float* Bv = xdbl  + ((size_t)b*CDBL + DTRANK)*LTOT + c*CHUNKL;
    const float* Cv = xdbl  + ((size_t)b*CDBL + DTRANK + DSTATE)*LTOT + c*CHUNKL;
    float h[DSTATE];
    #pragma unroll
    for (int n=0;n<DSTATE;n++) h[n] = Hinit[((size_t)bd*NC + c)*DSTATE + n];
    float Dd = Ds[d];
    float* yo = y + (size_t)bd*LTOT + c*CHUNKL;
    for (int t=0;t<CHUNKL;t++){
        float dt = dl[t]; float xt = xv[t]; float dx = dt*xt;
        float acc = Dd*xt;
        #pragma unroll
        for (int n=0;n<DSTATE;n++){
            float a = expf(dt*A[n]);
            h[n] = a*h[n] + dx*Bv[(size_t)n*LTOT + t];
            acc += h[n]*Cv[(size_t)n*LTOT + t];
        }
        yo[t] = acc;
    }
}

// ------------- K10: LN(y) * gelu(z) -> out_proj -> + xf  (LDS tile, 64 pos/block) -------------
__global__ __launch_bounds__(256) void k_gate_out(const float* __restrict__ y,
        const float* __restrict__ z, const float* __restrict__ onw, const float* __restrict__ onb,
        const float* __restrict__ Wout, const float* __restrict__ xf, float* __restrict__ out){
    __shared__ float ly[DINNER][65];
    int blk = blockIdx.x;             // BATCH * LTOT/64 = 512
    int b = blk >> 8; int l0 = (blk & 255) << 6;
    for (int i=threadIdx.x; i < DINNER*64; i += 256){
        int d = i >> 6, j = i & 63;
        ly[d][j] = y[((size_t)b*DINNER + d)*LTOT + l0 + j];
    }
    __syncthreads();
    int pos = threadIdx.x >> 2, part = threadIdx.x & 3;
    int l = l0 + pos;
    float s1=0.f, s2=0.f;
    for (int d=part; d<DINNER; d+=4){ float v = ly[d][pos]; s1+=v; s2+=v*v; }
    s1 += __shfl_xor(s1,1); s2 += __shfl_xor(s2,1);
    s1 += __shfl_xor(s1,2); s2 += __shfl_xor(s2,2);
    float mu  = s1*(1.0f/DINNER);
    float var = s2*(1.0f/DINNER) - mu*mu;
    float rs  = rsqrtf(var + 1e-5f);
    float acc[16];
    #pragma unroll
    for (int k=0;k<16;k++) acc[k]=0.f;
    const float* zb = z + ((size_t)b*LTOT + l)*DINNER;
    for (int d=0; d<DINNER; d++){
        float g = ((ly[d][pos]-mu)*rs*onw[d] + onb[d]) * gelu_exact(zb[d]);
        #pragma unroll
        for (int k=0;k<16;k++) acc[k] += g * Wout[(part*16+k)*DINNER + d];
    }
    #pragma unroll
    for (int k=0;k<16;k++){
        int o = part*16+k;
        out[((size_t)b*CDIM+o)*LTOT + l] = xf[((size_t)b*CDIM+o)*LTOT + l] + acc[k];
    }
}

// ------------- K11: wb_ln(norm2) + pin (64 -> 384) -------------
__global__ __launch_bounds__(256) void k_ln_pin(const float* __restrict__ x2,
        const float* __restrict__ nw, const float* __restrict__ nb,
        const float* __restrict__ Wp, float* __restrict__ h2){
    int wave = (blockIdx.x*256 + threadIdx.x) >> 6;
    int lane = threadIdx.x & 63;
    if (wave >= BATCH*LTOT) return;
    int b = wave >> 14, l = wave & (LTOT-1);
    float v = x2[((size_t)b*CDIM + lane)*LTOT + l];
    float s = v*v;
    #pragma unroll
    for (int off=32; off; off>>=1) s += __shfl_xor(s, off);
    float r  = rsqrtf(s * (1.0f/CDIM) + 1e-6f);
    float xn = v * r * nw[lane] + nb[lane];
    float acc[6];
    #pragma unroll
    for (int k=0;k<6;k++) acc[k]=0.f;
    for (int c=0;c<CDIM;c++){
        float xc = __shfl(xn, c);
        #pragma unroll
        for (int k=0;k<6;k++) acc[k] += xc * Wp[(k*64+lane)*CDIM + c];
    }
    #pragma unroll
    for (int k=0;k<6;k++) h2[((size_t)b*2*NHID + k*64 + lane)*LTOT + l] = acc[k];
}

// ------------- K12: dwconv2d 3x3 (no bias) + gelu-gate -------------
__global__ __launch_bounds__(256) void k_dwconv_gate(const float* __restrict__ h2,
        const float* __restrict__ dww, float* __restrict__ g){
    int idx = blockIdx.x*256 + threadIdx.x;
    if (idx >= BATCH*NHID*LTOT) return;
    int l = idx & (LTOT-1); int bc = idx >> 14; int ch = bc % NHID; int b = bc / NHID;
    int h = l >> 7, w = l & (WDIM-1);
    const float* b1 = h2 + ((size_t)b*2*NHID + ch)*LTOT;
    const float* b2 = b1 + (size_t)NHID*LTOT;
    float a1=0.f, a2=0.f;
    #pragma unroll
    for (int dh=-1; dh<=1; dh++){
        int hh = h+dh; if (hh<0||hh>=HDIM) continue;
        #pragma unroll
        for (int dw=-1; dw<=1; dw++){
            int ww = w+dw; if (ww<0||ww>=WDIM) continue;
            int tap = (dh+1)*3 + (dw+1);
            a1 += b1[hh*WDIM+ww] * dww[ch*9 + tap];
            a2 += b2[hh*WDIM+ww] * dww[(ch+NHID)*9 + tap];
        }
    }
    g[idx] = gelu_exact(a1)*a2;
}

// ------------- K13: pout (192 -> 64), LDS tile 32 pos/block -------------
__global__ __launch_bounds__(256) void k_pout(const float* __restrict__ g,
        const float* __restrict__ Wp, float* __restrict__ y2){
    __shared__ float lg[NHID][33];
    int blk = blockIdx.x;              // BATCH * LTOT/32 = 1024
    int b = blk >> 9; int l0 = (blk & 511) << 5;
    for (int i=threadIdx.x; i < NHID*32; i += 256){
        int c = i >> 5, j = i & 31;
        lg[c][j] = g[((size_t)b*NHID+c)*LTOT + l0 + j];
    }
    __syncthreads();
    int pos = threadIdx.x >> 3, part = threadIdx.x & 7;
    int l = l0 + pos;
    float acc[8];
    #pragma unroll
    for (int k=0;k<8;k++) acc[k]=0.f;
    for (int c=0;c<NHID;c++){
        float v = lg[c][pos];
        #pragma unroll
        for (int k=0;k<8;k++) acc[k] += v * Wp[(part*8+k)*NHID + c];
    }
    #pragma unroll
    for (int k=0;k<8;k++) y2[((size_t)b*CDIM + part*8+k)*LTOT + l] = acc[k];
}

// ------------- K14a: build per-channel 8x8 circular kernel from fft_p -------------
__global__ void k_fftker(const float* __restrict__ fp, float* __restrict__ kk){
    int c = threadIdx.x; if (c >= CDIM) return;
    const float PI4 = 0.78539816339744831f;
    for (int dm=0; dm<8; dm++){
        for (int dn=0; dn<8; dn++){
            float s = 0.f;
            for (int u=0; u<8; u++){
                for (int v=0; v<8; v++){
                    // Hermitian-extended multiplier M[u][v]
                    float m1 = (v<=4) ? fp[c*40 + u*5 + v]
                                      : fp[c*40 + ((8-u)&7)*5 + (8-v)];
                    int u2 = (8-u)&7, v2 = (8-v)&7;
                    float m2 = (v2<=4) ? fp[c*40 + u2*5 + v2]
                                       : fp[c*40 + ((8-u2)&7)*5 + (8-v2)];
                    float Ms = 0.5f*(m1+m2);
                    s += Ms * cosf(PI4 * (float)((u*dm + v*dn)&7));
                }
            }
            kk[c*64 + dm*8 + dn] = s * (1.0f/64.0f);
        }
    }
}

// ------------- K14b: per-patch circular conv + residual (in-place on d_out) -------------
__global__ __launch_bounds__(256) void k_patchconv_res(const float* __restrict__ y2,
        const float* __restrict__ kk, float* __restrict__ out){
    int idx = blockIdx.x*256 + threadIdx.x;
    if (idx >= BATCH*CDIM*LTOT) return;
    int l = idx & (LTOT-1); int bc = idx >> 14; int c = bc & (CDIM-1);
    int h = l >> 7, w = l & (WDIM-1);
    int hb = h>>3, hi = h&7, wb = w>>3, wi = w&7;
    const float* yb = y2 + (size_t)bc*LTOT + (hb*8)*WDIM + wb*8;
    const float* kc = kk + c*64;
    float acc = 0.f;
    #pragma unroll
    for (int m=0;m<8;m++){
        #pragma unroll
        for (int n=0;n<8;n++){
            acc += yb[m*WDIM + n] * kc[((hi-m)&7)*8 + ((wi-n)&7)];
        }
    }
    out[idx] += acc;
}

extern "C" void kernel_launch(void* const* d_in, const int* in_sizes, int n_in,
                              void* d_out, int out_size, void* d_ws, size_t ws_size,
                              hipStream_t stream){
    const float* x         = (const float*)d_in[0];
    const float* norm1_w   = (const float*)d_in[1];
    const float* norm1_b   = (const float*)d_in[2];
    const float* in_proj_w = (const float*)d_in[3];
    const float* conv2d_w  = (const float*)d_in[4];
    const float* conv2d_b  = (const float*)d_in[5];
    const float* x_proj_w  = (const float*)d_in[6];
    const float* x_conv_w  = (const float*)d_in[7];
    const float* x_conv_b  = (const float*)d_in[8];
    const float* dt_projs_w= (const float*)d_in[9];
    const float* dt_projs_b= (const float*)d_in[10];
    const float* A_logs    = (const float*)d_in[11];
    const float* Ds        = (const float*)d_in[12];
    const float* out_norm_w= (const float*)d_in[13];
    const float* out_norm_b= (const float*)d_in[14];
    const float* out_proj_w= (const float*)d_in[15];
    const float* norm2_w   = (const float*)d_in[16];
    const float* norm2_b   = (const float*)d_in[17];
    const float* pin_w     = (const float*)d_in[18];
    const float* dw_w      = (const float*)d_in[19];
    const float* fft_p     = (const float*)d_in[20];
    const float* pout_w    = (const float*)d_in[21];
    float* out = (float*)d_out;
    float* ws  = (float*)d_ws;

    float* xf    = ws + OFF_XF;
    float* z     = ws + OFF_Z;
    float* xin   = ws + OFF_XIN;
    float* xs    = ws + OFF_XS;
    float* delta = ws + OFF_DELTA;
    float* xdbl0 = ws + OFF_XDBL0;
    float* xdbl1 = ws + OFF_XDBL1;
    float* PS    = ws + OFF_PS;
    float* Hinit = ws + OFF_HINIT;
    float* y     = ws + OFF_Y;
    float* h2    = ws + OFF_H2;
    float* g     = ws + OFF_G;
    float* y2    = ws + OFF_Y2;
    float* kk    = ws + OFF_KK;

    // ---- SS2D branch ----
    k_flip<<<(BATCH*CDIM*LTOT+255)/256, 256, 0, stream>>>(x, xf);
    k_ln_inproj<<<(BATCH*LTOT*64+255)/256, 256, 0, stream>>>(xf, norm1_w, norm1_b, in_proj_w, xin, z);
    k_dwconv2d_gelu<<<(BATCH*DINNER*LTOT+255)/256, 256, 0, stream>>>(xin, conv2d_w, conv2d_b, xs);
    k_xproj<<<(BATCH*LTOT+255)/256, 256, 0, stream>>>(xs, x_proj_w, xdbl0);
    k_dwconv1d<<<(BATCH*CDBL*LTOT+255)/256, 256, 0, stream>>>(xdbl0, x_conv_w, x_conv_b, xdbl1);
    k_delta<<<(BATCH*DINNER*LTOT+255)/256, 256, 0, stream>>>(xdbl1, dt_projs_w, dt_projs_b, delta);
    k_scan1<<<(BATCH*DINNER*NC+255)/256, 256, 0, stream>>>(delta, xs, xdbl1, A_logs, PS);
    k_scan2<<<(BATCH*DINNER*DSTATE+255)/256, 256, 0, stream>>>(PS, Hinit);
    k_scan3<<<(BATCH*DINNER*NC+255)/256, 256, 0, stream>>>(delta, xs, xdbl1, A_logs, Ds, Hinit, y);
    k_gate_out<<<BATCH*(LTOT/64), 256, 0, stream>>>(y, z, out_norm_w, out_norm_b, out_proj_w, xf, out);

    // ---- EDFFN branch (out currently holds x2) ----
    k_ln_pin<<<(BATCH*LTOT*64+255)/256, 256, 0, stream>>>(out, norm2_w, norm2_b, pin_w, h2);
    k_dwconv_gate<<<(BATCH*NHID*LTOT+255)/256, 256, 0, stream>>>(h2, dw_w, g);
    k_pout<<<BATCH*(LTOT/32), 256, 0, stream>>>(g, pout_w, y2);
    k_fftker<<<1, 64, 0, stream>>>(fft_p, kk);
    k_patchconv_res<<<(BATCH*CDIM*LTOT+255)/256, 256, 0, stream>>>(y2, kk, out);
}

// Round 2
// 1903.797 us; speedup vs baseline: 1.4068x; 1.4068x over previous
//
#include <hip/hip_runtime.h>
#include <math.h>

#define BATCH   2
#define CDIM    64
#define DSTATE  8
#define DINNER  128
#define DTRANK  4
#define CDBL    20       // DTRANK + 2*DSTATE
#define HDIM    128
#define WDIM    128
#define LTOT    16384    // HDIM*WDIM
#define NHID    192      // HIDDEN
#define NC      256      // scan chunks
#define CHUNKL  64       // LTOT / NC

// ---- workspace offsets (floats) ----
static const size_t OFF_XF    = 0;            // 2*64*16384   = 2097152
static const size_t OFF_Z     = 2097152;      // (B,L,128)    = 4194304
static const size_t OFF_XIN   = 6291456;      // (B,128,L)    = 4194304
static const size_t OFF_XS    = 10485760;     // (B,128,L)    = 4194304
static const size_t OFF_DELTA = 14680064;     // (B,128,L)    = 4194304
static const size_t OFF_XDBL0 = 18874368;     // (B,20,L)     = 655360
static const size_t OFF_XDBL1 = 19529728;     // (B,20,L)     = 655360
static const size_t OFF_PS    = 20185088;     // 2*128*256*16 = 1048576
static const size_t OFF_HINIT = 21233664;     // 2*128*256*8  = 524288
static const size_t OFF_Y     = OFF_XIN;      // reuse xin
// EDFFN phase (reuses dead SS2D buffers)
static const size_t OFF_H2    = 0;            // (B,384,L)    = 12582912
static const size_t OFF_G     = 12582912;     // (B,192,L)    = 6291456
static const size_t OFF_Y2    = 18874368;     // (B,64,L)     = 2097152
static const size_t OFF_KK    = 21757952;     // 64*8*8       = 4096
// total floats = 21762048  (~87 MB)

__device__ __forceinline__ float gelu_exact(float x){
    return x * 0.5f * (1.0f + erff(x * 0.70710678118654752f));
}
__device__ __forceinline__ float softplus_f(float x){
    return (x > 20.0f) ? x : log1pf(expf(x));
}

// ---------------- K1: flip H,W ----------------
__global__ __launch_bounds__(256) void k_flip(const float* __restrict__ x, float* __restrict__ xf){
    int idx = blockIdx.x*256 + threadIdx.x;
    if (idx >= BATCH*CDIM*LTOT) return;
    int l = idx & (LTOT-1); int bc = idx >> 14;
    int h = l >> 7, w = l & (WDIM-1);
    xf[idx] = x[(size_t)bc*LTOT + (HDIM-1-h)*WDIM + (WDIM-1-w)];
}

// ------------- K2: wb_ln(norm1) + in_proj (wave per position) -------------
__global__ __launch_bounds__(256) void k_ln_inproj(const float* __restrict__ xf,
        const float* __restrict__ nw, const float* __restrict__ nb,
        const float* __restrict__ Wp, float* __restrict__ xin, float* __restrict__ z){
    int wave = (blockIdx.x*256 + threadIdx.x) >> 6;
    int lane = threadIdx.x & 63;
    if (wave >= BATCH*LTOT) return;
    int b = wave >> 14, l = wave & (LTOT-1);
    float v = xf[((size_t)b*CDIM + lane)*LTOT + l];
    float s = v*v;
    #pragma unroll
    for (int off=32; off; off>>=1) s += __shfl_xor(s, off);
    float r  = rsqrtf(s * (1.0f/CDIM) + 1e-6f);
    float xn = v * r * nw[lane] + nb[lane];
    float a0=0.f,a1=0.f,a2=0.f,a3=0.f;
    for (int c=0;c<CDIM;c++){
        float xc = __shfl(xn, c);
        a0 += xc * Wp[(lane      )*CDIM + c];
        a1 += xc * Wp[(lane + 64 )*CDIM + c];
        a2 += xc * Wp[(lane + 128)*CDIM + c];
        a3 += xc * Wp[(lane + 192)*CDIM + c];
    }
    xin[((size_t)b*DINNER + lane     )*LTOT + l] = a0;
    xin[((size_t)b*DINNER + lane + 64)*LTOT + l] = a1;
    z[((size_t)b*LTOT + l)*DINNER + lane     ] = a2;
    z[((size_t)b*LTOT + l)*DINNER + lane + 64] = a3;
}

// ------------- K3: depthwise conv2d 3x3 + gelu -------------
__global__ __launch_bounds__(256) void k_dwconv2d_gelu(const float* __restrict__ xin,
        const float* __restrict__ cw, const float* __restrict__ cb, float* __restrict__ xs){
    int idx = blockIdx.x*256 + threadIdx.x;
    if (idx >= BATCH*DINNER*LTOT) return;
    int l = idx & (LTOT-1); int bd = idx >> 14; int d = bd & (DINNER-1);
    int h = l >> 7, w = l & (WDIM-1);
    const float* base = xin + (size_t)bd*LTOT;
    float acc = cb[d];
    #pragma unroll
    for (int dh=-1; dh<=1; dh++){
        int hh = h+dh; if (hh<0||hh>=HDIM) continue;
        #pragma unroll
        for (int dw=-1; dw<=1; dw++){
            int ww = w+dw; if (ww<0||ww>=WDIM) continue;
            acc += base[hh*WDIM+ww] * cw[d*9 + (dh+1)*3 + (dw+1)];
        }
    }
    xs[idx] = gelu_exact(acc);
}

// ------------- K4: x_proj (128 -> 20) -------------
__global__ __launch_bounds__(256) void k_xproj(const float* __restrict__ xs,
        const float* __restrict__ Wx, float* __restrict__ xdbl_pre){
    int idx = blockIdx.x*256 + threadIdx.x;
    if (idx >= BATCH*LTOT) return;
    int b = idx >> 14, l = idx & (LTOT-1);
    float acc[CDBL];
    #pragma unroll
    for (int r=0;r<CDBL;r++) acc[r]=0.f;
    for (int d=0; d<DINNER; d++){
        float v = xs[((size_t)b*DINNER+d)*LTOT + l];
        #pragma unroll
        for (int r=0;r<CDBL;r++) acc[r] += v * Wx[r*DINNER+d];
    }
    #pragma unroll
    for (int r=0;r<CDBL;r++) xdbl_pre[((size_t)b*CDBL+r)*LTOT + l] = acc[r];
}

// ------------- K5: depthwise conv1d k=7 pad=3 + bias -------------
__global__ __launch_bounds__(256) void k_dwconv1d(const float* __restrict__ xp,
        const float* __restrict__ cw, const float* __restrict__ cb, float* __restrict__ xdbl){
    int idx = blockIdx.x*256 + threadIdx.x;
    if (idx >= BATCH*CDBL*LTOT) return;
    int l = idx & (LTOT-1); int br = idx >> 14; int r = br % CDBL;
    const float* base = xp + (size_t)br*LTOT;
    float acc = cb[r];
    #pragma unroll
    for (int k=0;k<7;k++){
        int t = l + k - 3;
        if (t>=0 && t<LTOT) acc += base[t]*cw[r*7+k];
    }
    xdbl[idx] = acc;
}

// ------------- K6: dts -> delta = softplus(dt_proj + bias) -------------
__global__ __launch_bounds__(256) void k_delta(const float* __restrict__ xdbl,
        const float* __restrict__ dtw, const float* __restrict__ dtb, float* __restrict__ delta){
    int idx = blockIdx.x*256 + threadIdx.x;
    if (idx >= BATCH*DINNER*LTOT) return;
    int l = idx & (LTOT-1); int bd = idx >> 14; int d = bd & (DINNER-1); int b = bd >> 7;
    const float* xb = xdbl + (size_t)b*CDBL*LTOT;
    float s = dtb[d];
    #pragma unroll
    for (int r=0;r<DTRANK;r++) s += xb[(size_t)r*LTOT + l] * dtw[d*DTRANK+r];
    delta[idx] = softplus_f(s);
}

// ------------- K7: scan pass1 (per-chunk P,S) -------------
__global__ __launch_bounds__(256) void k_scan1(const float* __restrict__ delta,
        const float* __restrict__ xs, const float* __restrict__ xdbl,
        const float* __restrict__ A_logs, float* __restrict__ PS){
    int idx = blockIdx.x*256 + threadIdx.x;
    if (idx >= BATCH*DINNER*NC) return;
    int c = idx & (NC-1); int bd = idx >> 8; int d = bd & (DINNER-1); int b = bd >> 7;
    float A[DSTATE];
    #pragma unroll
    for (int n=0;n<DSTATE;n++) A[n] = -expf(A_logs[d*DSTATE+n]);
    const float* dl = delta + (size_t)bd*LTOT + c*CHUNKL;
    const float* xv = xs    + (size_t)bd*LTOT + c*CHUNKL;
    const float* Bv = xdbl  + ((size_t)b*CDBL + DTRANK)*LTOT + c*CHUNKL;
    float h[DSTATE] = {0,0,0,0,0,0,0,0};
    float sdt = 0.f;
    for (int t=0;t<CHUNKL;t++){
        float dt = dl[t];
        float dx = dt * xv[t];
        sdt += dt;
        #pragma unroll
        for (int n=0;n<DSTATE;n++){
            float a = expf(dt*A[n]);
            h[n] = a*h[n] + dx*Bv[(size_t)n*LTOT + t];
        }
    }
    float* ps = PS + (size_t)idx*16;
    #pragma unroll
    for (int n=0;n<DSTATE;n++){ ps[n] = expf(sdt*A[n]); ps[8+n] = h[n]; }
}

// ------------- K8: cross-chunk scan -------------
__global__ __launch_bounds__(256) void k_scan2(const float* __restrict__ PS, float* __restrict__ Hinit){
    int idx = blockIdx.x*256 + threadIdx.x;
    if (idx >= BATCH*DINNER*DSTATE) return;
    int n = idx & (DSTATE-1); int bd = idx >> 3;
    float h = 0.f;
    for (int c=0;c<NC;c++){
        Hinit[((size_t)bd*NC + c)*DSTATE + n] = h;
        const float* ps = PS + ((size_t)bd*NC + c)*16;
        h = ps[n]*h + ps[8+n];
    }
}

// ------------- K9: scan pass2 (replay + y) -------------
__global__ __launch_bounds__(256) void k_scan3(const float* __restrict__ delta,
        const float* __restrict__ xs, const float* __restrict__ xdbl,
        const float* __restrict__ A_logs, const float* __restrict__ Ds,
        const float* __restrict__ Hinit, float* __restrict__ y){
    int idx = blockIdx.x*256 + threadIdx.x;
    if (idx >= BATCH*DINNER*NC) return;
    int c = idx & (NC-1); int bd = idx >> 8; int d = bd & (DINNER-1); int b = bd >> 7;
    float A[DSTATE];
    #pragma unroll
    for (int n=0;n<DSTATE;n++) A[n] = -expf(A_logs[d*DSTATE+n]);
    const float* dl = delta + (size_t)bd*LTOT + c*CHUNKL;
    const float* xv = xs    + (size_t)bd*LTOT + c*CHUNKL;
    const float* Bv = xdbl  + ((size_t)b*CDBL + DTRANK)*LTOT + c*CHUNKL;
    const float* Cv = xdbl  + ((size_t)b*CDBL + DTRANK + DSTATE)*LTOT + c*CHUNKL;
    float h[DSTATE];
    #pragma unroll
    for (int n=0;n<DSTATE;n++) h[n] = Hinit[((size_t)bd*NC + c)*DSTATE + n];
    float Dd = Ds[d];
    float* yo = y + (size_t)bd*LTOT + c*CHUNKL;
    for (int t=0;t<CHUNKL;t++){
        float dt = dl[t]; float xt = xv[t]; float dx = dt*xt;
        float acc = Dd*xt;
        #pragma unroll
        for (int n=0;n<DSTATE;n++){
            float a = expf(dt*A[n]);
            h[n] = a*h[n] + dx*Bv[(size_t)n*LTOT + t];
            acc += h[n]*Cv[(size_t)n*LTOT + t];
        }
        yo[t] = acc;
    }
}

// ------------- K10: LN(y) * gelu(z) -> out_proj -> + xf  (LDS tile, 64 pos/block) -------------
__global__ __launch_bounds__(256) void k_gate_out(const float* __restrict__ y,
        const float* __restrict__ z, const float* __restrict__ onw, const float* __restrict__ onb,
        const float* __restrict__ Wout, const float* __restrict__ xf, float* __restrict__ out){
    __shared__ float ly[DINNER][65];
    int blk = blockIdx.x;             // BATCH * LTOT/64 = 512
    int b = blk >> 8; int l0 = (blk & 255) << 6;
    for (int i=threadIdx.x; i < DINNER*64; i += 256){
        int d = i >> 6, j = i & 63;
        ly[d][j] = y[((size_t)b*DINNER + d)*LTOT + l0 + j];
    }
    __syncthreads();
    int pos = threadIdx.x >> 2, part = threadIdx.x & 3;
    int l = l0 + pos;
    float s1=0.f, s2=0.f;
    for (int d=part; d<DINNER; d+=4){ float v = ly[d][pos]; s1+=v; s2+=v*v; }
    s1 += __shfl_xor(s1,1); s2 += __shfl_xor(s2,1);
    s1 += __shfl_xor(s1,2); s2 += __shfl_xor(s2,2);
    float mu  = s1*(1.0f/DINNER);
    float var = s2*(1.0f/DINNER) - mu*mu;
    float rs  = rsqrtf(var + 1e-5f);
    float acc[16];
    #pragma unroll
    for (int k=0;k<16;k++) acc[k]=0.f;
    const float* zb = z + ((size_t)b*LTOT + l)*DINNER;
    for (int d=0; d<DINNER; d++){
        float g = ((ly[d][pos]-mu)*rs*onw[d] + onb[d]) * gelu_exact(zb[d]);
        #pragma unroll
        for (int k=0;k<16;k++) acc[k] += g * Wout[(part*16+k)*DINNER + d];
    }
    #pragma unroll
    for (int k=0;k<16;k++){
        int o = part*16+k;
        out[((size_t)b*CDIM+o)*LTOT + l] = xf[((size_t)b*CDIM+o)*LTOT + l] + acc[k];
    }
}

// ------------- K11: wb_ln(norm2) + pin (64 -> 384) -------------
__global__ __launch_bounds__(256) void k_ln_pin(const float* __restrict__ x2,
        const float* __restrict__ nw, const float* __restrict__ nb,
        const float* __restrict__ Wp, float* __restrict__ h2){
    int wave = (blockIdx.x*256 + threadIdx.x) >> 6;
    int lane = threadIdx.x & 63;
    if (wave >= BATCH*LTOT) return;
    int b = wave >> 14, l = wave & (LTOT-1);
    float v = x2[((size_t)b*CDIM + lane)*LTOT + l];
    float s = v*v;
    #pragma unroll
    for (int off=32; off; off>>=1) s += __shfl_xor(s, off);
    float r  = rsqrtf(s * (1.0f/CDIM) + 1e-6f);
    float xn = v * r * nw[lane] + nb[lane];
    float acc[6];
    #pragma unroll
    for (int k=0;k<6;k++) acc[k]=0.f;
    for (int c=0;c<CDIM;c++){
        float xc = __shfl(xn, c);
        #pragma unroll
        for (int k=0;k<6;k++) acc[k] += xc * Wp[(k*64+lane)*CDIM + c];
    }
    #pragma unroll
    for (int k=0;k<6;k++) h2[((size_t)b*2*NHID + k*64 + lane)*LTOT + l] = acc[k];
}

// ------------- K12: dwconv2d 3x3 (no bias) + gelu-gate -------------
__global__ __launch_bounds__(256) void k_dwconv_gate(const float* __restrict__ h2,
        const float* __restrict__ dww, float* __restrict__ g){
    int idx = blockIdx.x*256 + threadIdx.x;
    if (idx >= BATCH*NHID*LTOT) return;
    int l = idx & (LTOT-1); int bc = idx >> 14; int ch = bc % NHID; int b = bc / NHID;
    int h = l >> 7, w = l & (WDIM-1);
    const float* b1 = h2 + ((size_t)b*2*NHID + ch)*LTOT;
    const float* b2 = b1 + (size_t)NHID*LTOT;
    float a1=0.f, a2=0.f;
    #pragma unroll
    for (int dh=-1; dh<=1; dh++){
        int hh = h+dh; if (hh<0||hh>=HDIM) continue;
        #pragma unroll
        for (int dw=-1; dw<=1; dw++){
            int ww = w+dw; if (ww<0||ww>=WDIM) continue;
            int tap = (dh+1)*3 + (dw+1);
            a1 += b1[hh*WDIM+ww] * dww[ch*9 + tap];
            a2 += b2[hh*WDIM+ww] * dww[(ch+NHID)*9 + tap];
        }
    }
    g[idx] = gelu_exact(a1)*a2;
}

// ------------- K13: pout (192 -> 64), LDS tile 32 pos/block -------------
__global__ __launch_bounds__(256) void k_pout(const float* __restrict__ g,
        const float* __restrict__ Wp, float* __restrict__ y2){
    __shared__ float lg[NHID][33];
    int blk = blockIdx.x;              // BATCH * LTOT/32 = 1024
    int b = blk >> 9; int l0 = (blk & 511) << 5;
    for (int i=threadIdx.x; i < NHID*32; i += 256){
        int c = i >> 5, j = i & 31;
        lg[c][j] = g[((size_t)b*NHID+c)*LTOT + l0 + j];
    }
    __syncthreads();
    int pos = threadIdx.x >> 3, part = threadIdx.x & 7;
    int l = l0 + pos;
    float acc[8];
    #pragma unroll
    for (int k=0;k<8;k++) acc[k]=0.f;
    for (int c=0;c<NHID;c++){
        float v = lg[c][pos];
        #pragma unroll
        for (int k=0;k<8;k++) acc[k] += v * Wp[(part*8+k)*NHID + c];
    }
    #pragma unroll
    for (int k=0;k<8;k++) y2[((size_t)b*CDIM + part*8+k)*LTOT + l] = acc[k];
}

// ------------- K14a: build per-channel 8x8 circular kernel from fft_p -------------
// Parallelized: one thread per (channel, tap) = 4096 threads.
// cos(pi/4 * k) for k in 0..7 is an exact 8-entry table -> no transcendentals.
__global__ __launch_bounds__(256) void k_fftker(const float* __restrict__ fp, float* __restrict__ kk){
    int idx = blockIdx.x*256 + threadIdx.x;
    if (idx >= CDIM*64) return;
    int c = idx >> 6, tap = idx & 63;
    int dm = tap >> 3, dn = tap & 7;
    const float R = 0.70710678118654752f;
    const float ct[8] = {1.f, R, 0.f, -R, -1.f, -R, 0.f, R};
    const float* fc = fp + c*40;
    float s = 0.f;
    #pragma unroll
    for (int u=0; u<8; u++){
        #pragma unroll
        for (int v=0; v<8; v++){
            float m1 = (v<=4) ? fc[u*5 + v]
                              : fc[((8-u)&7)*5 + (8-v)];
            int u2 = (8-u)&7, v2 = (8-v)&7;
            float m2 = (v2<=4) ? fc[u2*5 + v2]
                               : fc[((8-u2)&7)*5 + (8-v2)];
            float Ms = 0.5f*(m1+m2);
            s += Ms * ct[(u*dm + v*dn)&7];
        }
    }
    kk[c*64 + dm*8 + dn] = s * (1.0f/64.0f);
}

// ------------- K14b: per-patch circular conv + residual (in-place on d_out) -------------
__global__ __launch_bounds__(256) void k_patchconv_res(const float* __restrict__ y2,
        const float* __restrict__ kk, float* __restrict__ out){
    int idx = blockIdx.x*256 + threadIdx.x;
    if (idx >= BATCH*CDIM*LTOT) return;
    int l = idx & (LTOT-1); int bc = idx >> 14; int c = bc & (CDIM-1);
    int h = l >> 7, w = l & (WDIM-1);
    int hb = h>>3, hi = h&7, wb = w>>3, wi = w&7;
    const float* yb = y2 + (size_t)bc*LTOT + (hb*8)*WDIM + wb*8;
    const float* kc = kk + c*64;
    float acc = 0.f;
    #pragma unroll
    for (int m=0;m<8;m++){
        #pragma unroll
        for (int n=0;n<8;n++){
            acc += yb[m*WDIM + n] * kc[((hi-m)&7)*8 + ((wi-n)&7)];
        }
    }
    out[idx] += acc;
}

extern "C" void kernel_launch(void* const* d_in, const int* in_sizes, int n_in,
                              void* d_out, int out_size, void* d_ws, size_t ws_size,
                              hipStream_t stream){
    const float* x         = (const float*)d_in[0];
    const float* norm1_w   = (const float*)d_in[1];
    const float* norm1_b   = (const float*)d_in[2];
    const float* in_proj_w = (const float*)d_in[3];
    const float* conv2d_w  = (const float*)d_in[4];
    const float* conv2d_b  = (const float*)d_in[5];
    const float* x_proj_w  = (const float*)d_in[6];
    const float* x_conv_w  = (const float*)d_in[7];
    const float* x_conv_b  = (const float*)d_in[8];
    const float* dt_projs_w= (const float*)d_in[9];
    const float* dt_projs_b= (const float*)d_in[10];
    const float* A_logs    = (const float*)d_in[11];
    const float* Ds        = (const float*)d_in[12];
    const float* out_norm_w= (const float*)d_in[13];
    const float* out_norm_b= (const float*)d_in[14];
    const float* out_proj_w= (const float*)d_in[15];
    const float* norm2_w   = (const float*)d_in[16];
    const float* norm2_b   = (const float*)d_in[17];
    const float* pin_w     = (const float*)d_in[18];
    const float* dw_w      = (const float*)d_in[19];
    const float* fft_p     = (const float*)d_in[20];
    const float* pout_w    = (const float*)d_in[21];
    float* out = (float*)d_out;
    float* ws  = (float*)d_ws;

    float* xf    = ws + OFF_XF;
    float* z     = ws + OFF_Z;
    float* xin   = ws + OFF_XIN;
    float* xs    = ws + OFF_XS;
    float* delta = ws + OFF_DELTA;
    float* xdbl0 = ws + OFF_XDBL0;
    float* xdbl1 = ws + OFF_XDBL1;
    float* PS    = ws + OFF_PS;
    float* Hinit = ws + OFF_HINIT;
    float* y     = ws + OFF_Y;
    float* h2    = ws + OFF_H2;
    float* g     = ws + OFF_G;
    float* y2    = ws + OFF_Y2;
    float* kk    = ws + OFF_KK;

    // ---- SS2D branch ----
    k_flip<<<(BATCH*CDIM*LTOT+255)/256, 256, 0, stream>>>(x, xf);
    k_ln_inproj<<<(BATCH*LTOT*64+255)/256, 256, 0, stream>>>(xf, norm1_w, norm1_b, in_proj_w, xin, z);
    k_dwconv2d_gelu<<<(BATCH*DINNER*LTOT+255)/256, 256, 0, stream>>>(xin, conv2d_w, conv2d_b, xs);
    k_xproj<<<(BATCH*LTOT+255)/256, 256, 0, stream>>>(xs, x_proj_w, xdbl0);
    k_dwconv1d<<<(BATCH*CDBL*LTOT+255)/256, 256, 0, stream>>>(xdbl0, x_conv_w, x_conv_b, xdbl1);
    k_delta<<<(BATCH*DINNER*LTOT+255)/256, 256, 0, stream>>>(xdbl1, dt_projs_w, dt_projs_b, delta);
    k_scan1<<<(BATCH*DINNER*NC+255)/256, 256, 0, stream>>>(delta, xs, xdbl1, A_logs, PS);
    k_scan2<<<(BATCH*DINNER*DSTATE+255)/256, 256, 0, stream>>>(PS, Hinit);
    k_scan3<<<(BATCH*DINNER*NC+255)/256, 256, 0, stream>>>(delta, xs, xdbl1, A_logs, Ds, Hinit, y);
    k_gate_out<<<BATCH*(LTOT/64), 256, 0, stream>>>(y, z, out_norm_w, out_norm_b, out_proj_w, xf, out);

    // ---- EDFFN branch (out currently holds x2) ----
    k_ln_pin<<<(BATCH*LTOT*64+255)/256, 256, 0, stream>>>(out, norm2_w, norm2_b, pin_w, h2);
    k_dwconv_gate<<<(BATCH*NHID*LTOT+255)/256, 256, 0, stream>>>(h2, dw_w, g);
    k_pout<<<BATCH*(LTOT/32), 256, 0, stream>>>(g, pout_w, y2);
    k_fftker<<<(CDIM*64+255)/256, 256, 0, stream>>>(fft_p, kk);
    k_patchconv_res<<<(BATCH*CDIM*LTOT+255)/256, 256, 0, stream>>>(y2, kk, out);
}

// Round 3
// 587.664 us; speedup vs baseline: 4.5574x; 3.2396x over previous
//
#include <hip/hip_runtime.h>
#include <math.h>

#define BATCH   2
#define CDIM    64
#define DSTATE  8
#define DINNER  128
#define DTRANK  4
#define CDBL    20       // DTRANK + 2*DSTATE
#define HDIM    128
#define WDIM    128
#define LTOT    16384    // HDIM*WDIM
#define NHID    192      // HIDDEN
#define NC      256      // scan chunks
#define CHUNKL  64       // LTOT / NC

// ---- workspace offsets (floats) ----
static const size_t OFF_XF    = 0;            // 2*64*16384   = 2097152
static const size_t OFF_Z     = 2097152;      // (B,128,L)    = 4194304  (channel-major now)
static const size_t OFF_XIN   = 6291456;      // (B,128,L)    = 4194304
static const size_t OFF_XS    = 10485760;     // (B,128,L)    = 4194304
static const size_t OFF_XDBL0 = 18874368;     // (B,20,L)     = 655360
static const size_t OFF_XDBL1 = 19529728;     // (B,20,L)     = 655360
static const size_t OFF_PS    = 20185088;     // 2*128*256*16 = 1048576
static const size_t OFF_HINIT = 21233664;     // 2*128*256*8  = 524288
static const size_t OFF_Y     = OFF_XIN;      // reuse xin
// EDFFN phase (reuses dead SS2D buffers)
static const size_t OFF_H2    = 0;            // (B,384,L)    = 12582912
static const size_t OFF_G     = 12582912;     // (B,192,L)    = 6291456
static const size_t OFF_Y2    = 18874368;     // (B,64,L)     = 2097152
static const size_t OFF_KK    = 21757952;     // 64*8*8       = 4096

__device__ __forceinline__ float gelu_exact(float x){
    return x * 0.5f * (1.0f + erff(x * 0.70710678118654752f));
}
__device__ __forceinline__ float softplus_f(float x){
    return (x > 20.0f) ? x : log1pf(expf(x));
}

// ---------------- K1: flip H,W ----------------
__global__ __launch_bounds__(256) void k_flip(const float* __restrict__ x, float* __restrict__ xf){
    int idx = blockIdx.x*256 + threadIdx.x;
    if (idx >= BATCH*CDIM*LTOT) return;
    int l = idx & (LTOT-1); int bc = idx >> 14;
    int h = l >> 7, w = l & (WDIM-1);
    xf[idx] = x[(size_t)bc*LTOT + (HDIM-1-h)*WDIM + (WDIM-1-w)];
}

// ------------- K2: wb_ln(norm1) + in_proj, LDS-tiled (64 pos/block) -------------
// outputs: xin (B,128,L) channel-major, z (B,128,L) channel-major
__global__ __launch_bounds__(256) void k_ln_inproj(const float* __restrict__ xf,
        const float* __restrict__ nw, const float* __restrict__ nb,
        const float* __restrict__ Wp, float* __restrict__ xin, float* __restrict__ z){
    __shared__ float lx[CDIM][65];
    __shared__ float pr[4][64];
    __shared__ float rsA[64];
    int b = blockIdx.x >> 8;
    int l0 = (blockIdx.x & 255) << 6;
    int tid = threadIdx.x;
    for (int i=tid; i<CDIM*64; i+=256){
        int ch = i>>6, j = i&63;
        lx[ch][j] = xf[((size_t)b*CDIM+ch)*LTOT + l0 + j];
    }
    __syncthreads();
    {
        int pos = tid & 63, q = tid >> 6;
        float s = 0.f;
        for (int c=q*16; c<q*16+16; c++){ float v = lx[c][pos]; s += v*v; }
        pr[q][pos] = s;
    }
    __syncthreads();
    if (tid < 64){
        float t = pr[0][tid]+pr[1][tid]+pr[2][tid]+pr[3][tid];
        rsA[tid] = rsqrtf(t*(1.0f/CDIM) + 1e-6f);
    }
    __syncthreads();
    for (int i=tid; i<CDIM*64; i+=256){
        int ch = i>>6, j = i&63;
        lx[ch][j] = lx[ch][j]*rsA[j]*nw[ch] + nb[ch];
    }
    __syncthreads();
    int j = tid & 63, grp = tid >> 6;   // wave grp handles 64 of 256 outputs
    for (int half=0; half<2; half++){
        int o0 = grp*64 + half*32;
        float acc[32];
        #pragma unroll
        for (int oi=0;oi<32;oi++) acc[oi]=0.f;
        for (int cb=0; cb<8; cb++){
            float xv[8];
            #pragma unroll
            for (int cc=0;cc<8;cc++) xv[cc] = lx[cb*8+cc][j];
            #pragma unroll
            for (int oi=0;oi<32;oi++){
                const float* wr = Wp + (size_t)(o0+oi)*CDIM + cb*8;
                #pragma unroll
                for (int cc=0;cc<8;cc++) acc[oi] += xv[cc]*wr[cc];
            }
        }
        #pragma unroll
        for (int oi=0;oi<32;oi++){
            int o = o0+oi;
            float* dst = (o < DINNER) ? (xin + ((size_t)b*DINNER + o)*LTOT)
                                      : (z   + ((size_t)b*DINNER + (o-DINNER))*LTOT);
            dst[l0 + j] = acc[oi];
        }
    }
}

// ------------- K3: depthwise conv2d 3x3 + gelu -------------
__global__ __launch_bounds__(256) void k_dwconv2d_gelu(const float* __restrict__ xin,
        const float* __restrict__ cw, const float* __restrict__ cb, float* __restrict__ xs){
    int idx = blockIdx.x*256 + threadIdx.x;
    if (idx >= BATCH*DINNER*LTOT) return;
    int l = idx & (LTOT-1); int bd = idx >> 14; int d = bd & (DINNER-1);
    int h = l >> 7, w = l & (WDIM-1);
    const float* base = xin + (size_t)bd*LTOT;
    float acc = cb[d];
    #pragma unroll
    for (int dh=-1; dh<=1; dh++){
        int hh = h+dh; if (hh<0||hh>=HDIM) continue;
        #pragma unroll
        for (int dw=-1; dw<=1; dw++){
            int ww = w+dw; if (ww<0||ww>=WDIM) continue;
            acc += base[hh*WDIM+ww] * cw[d*9 + (dh+1)*3 + (dw+1)];
        }
    }
    xs[idx] = gelu_exact(acc);
}

// ------------- K4: x_proj (128 -> 20) -------------
__global__ __launch_bounds__(256) void k_xproj(const float* __restrict__ xs,
        const float* __restrict__ Wx, float* __restrict__ xdbl_pre){
    int idx = blockIdx.x*256 + threadIdx.x;
    if (idx >= BATCH*LTOT) return;
    int b = idx >> 14, l = idx & (LTOT-1);
    float acc[CDBL];
    #pragma unroll
    for (int r=0;r<CDBL;r++) acc[r]=0.f;
    for (int d=0; d<DINNER; d++){
        float v = xs[((size_t)b*DINNER+d)*LTOT + l];
        #pragma unroll
        for (int r=0;r<CDBL;r++) acc[r] += v * Wx[r*DINNER+d];
    }
    #pragma unroll
    for (int r=0;r<CDBL;r++) xdbl_pre[((size_t)b*CDBL+r)*LTOT + l] = acc[r];
}

// ------------- K5: depthwise conv1d k=7 pad=3 + bias -------------
__global__ __launch_bounds__(256) void k_dwconv1d(const float* __restrict__ xp,
        const float* __restrict__ cw, const float* __restrict__ cb, float* __restrict__ xdbl){
    int idx = blockIdx.x*256 + threadIdx.x;
    if (idx >= BATCH*CDBL*LTOT) return;
    int l = idx & (LTOT-1); int br = idx >> 14; int r = br % CDBL;
    const float* base = xp + (size_t)br*LTOT;
    float acc = cb[r];
    #pragma unroll
    for (int k=0;k<7;k++){
        int t = l + k - 3;
        if (t>=0 && t<LTOT) acc += base[t]*cw[r*7+k];
    }
    xdbl[idx] = acc;
}

// ------------- K7: scan pass1 — intra-wave parallel scan, lane = timestep -------------
// wave W: c = W&255 (chunk), bd = W>>8. delta computed inline from xdbl.
__global__ __launch_bounds__(256) void k_scan1(const float* __restrict__ xdbl,
        const float* __restrict__ xs, const float* __restrict__ A_logs,
        const float* __restrict__ dtw, const float* __restrict__ dtb,
        float* __restrict__ PS){
    int gtid = blockIdx.x*256 + threadIdx.x;
    int W = gtid >> 6;
    int lane = threadIdx.x & 63;
    int c = W & (NC-1);
    int bd = W >> 8;
    int d = bd & (DINNER-1);
    int b = bd >> 7;
    int l = c*CHUNKL + lane;
    const float* xb = xdbl + (size_t)b*CDBL*LTOT;
    float dtr = dtb[d];
    #pragma unroll
    for (int r=0;r<DTRANK;r++) dtr += xb[(size_t)r*LTOT + l] * dtw[d*DTRANK+r];
    float dt = softplus_f(dtr);
    float xv = xs[(size_t)bd*LTOT + l];
    float A[DSTATE], u[DSTATE];
    float dx = dt*xv;
    #pragma unroll
    for (int n=0;n<DSTATE;n++){
        A[n] = -expf(A_logs[d*DSTATE+n]);
        u[n] = dx * xb[(size_t)(DTRANK+n)*LTOT + l];
    }
    // inclusive prefix sum of dt over lanes
    float cum = dt;
    #pragma unroll
    for (int k=1;k<64;k<<=1){
        float v = __shfl_up(cum, k);
        if (lane >= k) cum += v;
    }
    // inclusive scan of u with decay exp(A*(cum_i - cum_{i-k}))
    #pragma unroll
    for (int k=1;k<64;k<<=1){
        float cp = __shfl_up(cum, k);
        float up[DSTATE];
        #pragma unroll
        for (int n=0;n<DSTATE;n++) up[n] = __shfl_up(u[n], k);
        if (lane >= k){
            float dc = cum - cp;
            #pragma unroll
            for (int n=0;n<DSTATE;n++) u[n] += __expf(A[n]*dc) * up[n];
        }
    }
    if (lane == 63){
        float* ps = PS + (size_t)W*16;
        #pragma unroll
        for (int n=0;n<DSTATE;n++){ ps[n] = __expf(A[n]*cum); ps[8+n] = u[n]; }
    }
}

// ------------- K8: cross-chunk scan -------------
__global__ __launch_bounds__(256) void k_scan2(const float* __restrict__ PS, float* __restrict__ Hinit){
    int idx = blockIdx.x*256 + threadIdx.x;
    if (idx >= BATCH*DINNER*DSTATE) return;
    int n = idx & (DSTATE-1); int bd = idx >> 3;
    float h = 0.f;
    for (int c=0;c<NC;c++){
        Hinit[((size_t)bd*NC + c)*DSTATE + n] = h;
        const float* ps = PS + ((size_t)bd*NC + c)*16;
        h = ps[n]*h + ps[8+n];
    }
}

// ------------- K9: scan pass2 — replay with Hinit, emit y -------------
__global__ __launch_bounds__(256) void k_scan3(const float* __restrict__ xdbl,
        const float* __restrict__ xs, const float* __restrict__ A_logs,
        const float* __restrict__ dtw, const float* __restrict__ dtb,
        const float* __restrict__ Ds, const float* __restrict__ Hinit,
        float* __restrict__ y){
    int gtid = blockIdx.x*256 + threadIdx.x;
    int W = gtid >> 6;
    int lane = threadIdx.x & 63;
    int c = W & (NC-1);
    int bd = W >> 8;
    int d = bd & (DINNER-1);
    int b = bd >> 7;
    int l = c*CHUNKL + lane;
    const float* xb = xdbl + (size_t)b*CDBL*LTOT;
    float dtr = dtb[d];
    #pragma unroll
    for (int r=0;r<DTRANK;r++) dtr += xb[(size_t)r*LTOT + l] * dtw[d*DTRANK+r];
    float dt = softplus_f(dtr);
    float xv = xs[(size_t)bd*LTOT + l];
    float A[DSTATE], u[DSTATE];
    float dx = dt*xv;
    #pragma unroll
    for (int n=0;n<DSTATE;n++){
        A[n] = -expf(A_logs[d*DSTATE+n]);
        u[n] = dx * xb[(size_t)(DTRANK+n)*LTOT + l];
    }
    float cum = dt;
    #pragma unroll
    for (int k=1;k<64;k<<=1){
        float v = __shfl_up(cum, k);
        if (lane >= k) cum += v;
    }
    #pragma unroll
    for (int k=1;k<64;k<<=1){
        float cp = __shfl_up(cum, k);
        float up[DSTATE];
        #pragma unroll
        for (int n=0;n<DSTATE;n++) up[n] = __shfl_up(u[n], k);
        if (lane >= k){
            float dc = cum - cp;
            #pragma unroll
            for (int n=0;n<DSTATE;n++) u[n] += __expf(A[n]*dc) * up[n];
        }
    }
    const float* hi = Hinit + ((size_t)bd*NC + c)*DSTATE;
    float acc = Ds[d]*xv;
    #pragma unroll
    for (int n=0;n<DSTATE;n++){
        float Cv = xb[(size_t)(DTRANK+DSTATE+n)*LTOT + l];
        float h = u[n] + hi[n]*__expf(A[n]*cum);
        acc += h*Cv;
    }
    y[(size_t)bd*LTOT + l] = acc;
}

// ------------- K10: LN(y)*gelu(z) -> out_proj -> + xf, LDS-tiled -------------
__global__ __launch_bounds__(256) void k_gate_out(const float* __restrict__ y,
        const float* __restrict__ z, const float* __restrict__ onw, const float* __restrict__ onb,
        const float* __restrict__ Wout, const float* __restrict__ xf, float* __restrict__ out){
    __shared__ float ly[DINNER][65];
    __shared__ float pr1[4][64], pr2[4][64];
    __shared__ float muA[64], rsA[64];
    int b = blockIdx.x >> 8;
    int l0 = (blockIdx.x & 255) << 6;
    int tid = threadIdx.x;
    for (int i=tid; i<DINNER*64; i+=256){
        int dd = i>>6, j = i&63;
        ly[dd][j] = y[((size_t)b*DINNER+dd)*LTOT + l0 + j];
    }
    __syncthreads();
    {
        int pos = tid & 63, q = tid >> 6;
        float s1=0.f, s2=0.f;
        for (int dd=q*32; dd<q*32+32; dd++){ float v = ly[dd][pos]; s1+=v; s2+=v*v; }
        pr1[q][pos]=s1; pr2[q][pos]=s2;
    }
    __syncthreads();
    if (tid < 64){
        float s1 = pr1[0][tid]+pr1[1][tid]+pr1[2][tid]+pr1[3][tid];
        float s2 = pr2[0][tid]+pr2[1][tid]+pr2[2][tid]+pr2[3][tid];
        float mu = s1*(1.0f/DINNER);
        float var = s2*(1.0f/DINNER) - mu*mu;
        muA[tid]=mu; rsA[tid]=rsqrtf(var + 1e-5f);
    }
    __syncthreads();
    for (int i=tid; i<DINNER*64; i+=256){
        int dd = i>>6, j = i&63;
        float zv = z[((size_t)b*DINNER+dd)*LTOT + l0 + j];
        ly[dd][j] = ((ly[dd][j]-muA[j])*rsA[j]*onw[dd] + onb[dd]) * gelu_exact(zv);
    }
    __syncthreads();
    int j = tid & 63, grp = tid >> 6;
    int o0 = grp*16;
    float acc[16];
    #pragma unroll
    for (int oi=0;oi<16;oi++) acc[oi]=0.f;
    for (int cb=0; cb<16; cb++){
        float xv[8];
        #pragma unroll
        for (int cc=0;cc<8;cc++) xv[cc] = ly[cb*8+cc][j];
        #pragma unroll
        for (int oi=0;oi<16;oi++){
            const float* wr = Wout + (size_t)(o0+oi)*DINNER + cb*8;
            #pragma unroll
            for (int cc=0;cc<8;cc++) acc[oi] += xv[cc]*wr[cc];
        }
    }
    #pragma unroll
    for (int oi=0;oi<16;oi++){
        size_t off = ((size_t)b*CDIM + o0+oi)*LTOT + l0 + j;
        out[off] = xf[off] + acc[oi];
    }
}

// ------------- K11: wb_ln(norm2) + pin (64 -> 384), LDS-tiled -------------
__global__ __launch_bounds__(256) void k_ln_pin(const float* __restrict__ x2,
        const float* __restrict__ nw, const float* __restrict__ nb,
        const float* __restrict__ Wp, float* __restrict__ h2){
    __shared__ float lx[CDIM][65];
    __shared__ float pr[4][64];
    __shared__ float rsA[64];
    int b = blockIdx.x >> 8;
    int l0 = (blockIdx.x & 255) << 6;
    int tid = threadIdx.x;
    for (int i=tid; i<CDIM*64; i+=256){
        int ch = i>>6, j = i&63;
        lx[ch][j] = x2[((size_t)b*CDIM+ch)*LTOT + l0 + j];
    }
    __syncthreads();
    {
        int pos = tid & 63, q = tid >> 6;
        float s = 0.f;
        for (int c=q*16; c<q*16+16; c++){ float v = lx[c][pos]; s += v*v; }
        pr[q][pos] = s;
    }
    __syncthreads();
    if (tid < 64){
        float t = pr[0][tid]+pr[1][tid]+pr[2][tid]+pr[3][tid];
        rsA[tid] = rsqrtf(t*(1.0f/CDIM) + 1e-6f);
    }
    __syncthreads();
    for (int i=tid; i<CDIM*64; i+=256){
        int ch = i>>6, j = i&63;
        lx[ch][j] = lx[ch][j]*rsA[j]*nw[ch] + nb[ch];
    }
    __syncthreads();
    int j = tid & 63, grp = tid >> 6;   // wave grp handles 96 of 384 outputs
    for (int chunk=0; chunk<3; chunk++){
        int o0 = grp*96 + chunk*32;
        float acc[32];
        #pragma unroll
        for (int oi=0;oi<32;oi++) acc[oi]=0.f;
        for (int cb=0; cb<8; cb++){
            float xv[8];
            #pragma unroll
            for (int cc=0;cc<8;cc++) xv[cc] = lx[cb*8+cc][j];
            #pragma unroll
            for (int oi=0;oi<32;oi++){
                const float* wr = Wp + (size_t)(o0+oi)*CDIM + cb*8;
                #pragma unroll
                for (int cc=0;cc<8;cc++) acc[oi] += xv[cc]*wr[cc];
            }
        }
        #pragma unroll
        for (int oi=0;oi<32;oi++){
            h2[((size_t)b*2*NHID + o0+oi)*LTOT + l0 + j] = acc[oi];
        }
    }
}

// ------------- K12: dwconv2d 3x3 (no bias) + gelu-gate -------------
__global__ __launch_bounds__(256) void k_dwconv_gate(const float* __restrict__ h2,
        const float* __restrict__ dww, float* __restrict__ g){
    int idx = blockIdx.x*256 + threadIdx.x;
    if (idx >= BATCH*NHID*LTOT) return;
    int l = idx & (LTOT-1); int bc = idx >> 14; int ch = bc % NHID; int b = bc / NHID;
    int h = l >> 7, w = l & (WDIM-1);
    const float* b1 = h2 + ((size_t)b*2*NHID + ch)*LTOT;
    const float* b2 = b1 + (size_t)NHID*LTOT;
    float a1=0.f, a2=0.f;
    #pragma unroll
    for (int dh=-1; dh<=1; dh++){
        int hh = h+dh; if (hh<0||hh>=HDIM) continue;
        #pragma unroll
        for (int dw=-1; dw<=1; dw++){
            int ww = w+dw; if (ww<0||ww>=WDIM) continue;
            int tap = (dh+1)*3 + (dw+1);
            a1 += b1[hh*WDIM+ww] * dww[ch*9 + tap];
            a2 += b2[hh*WDIM+ww] * dww[(ch+NHID)*9 + tap];
        }
    }
    g[idx] = gelu_exact(a1)*a2;
}

// ------------- K13: pout (192 -> 64), LDS-tiled 64 pos/block -------------
__global__ __launch_bounds__(256) void k_pout(const float* __restrict__ g,
        const float* __restrict__ Wp, float* __restrict__ y2){
    __shared__ float lg[NHID][65];
    int b = blockIdx.x >> 8;
    int l0 = (blockIdx.x & 255) << 6;
    int tid = threadIdx.x;
    for (int i=tid; i<NHID*64; i+=256){
        int c = i>>6, j = i&63;
        lg[c][j] = g[((size_t)b*NHID+c)*LTOT + l0 + j];
    }
    __syncthreads();
    int j = tid & 63, grp = tid >> 6;
    int o0 = grp*16;
    float acc[16];
    #pragma unroll
    for (int oi=0;oi<16;oi++) acc[oi]=0.f;
    for (int cb=0; cb<24; cb++){
        float xv[8];
        #pragma unroll
        for (int cc=0;cc<8;cc++) xv[cc] = lg[cb*8+cc][j];
        #pragma unroll
        for (int oi=0;oi<16;oi++){
            const float* wr = Wp + (size_t)(o0+oi)*NHID + cb*8;
            #pragma unroll
            for (int cc=0;cc<8;cc++) acc[oi] += xv[cc]*wr[cc];
        }
    }
    #pragma unroll
    for (int oi=0;oi<16;oi++){
        y2[((size_t)b*CDIM + o0+oi)*LTOT + l0 + j] = acc[oi];
    }
}

// ------------- K14a: build per-channel 8x8 circular kernel from fft_p -------------
__global__ __launch_bounds__(256) void k_fftker(const float* __restrict__ fp, float* __restrict__ kk){
    int idx = blockIdx.x*256 + threadIdx.x;
    if (idx >= CDIM*64) return;
    int c = idx >> 6, tap = idx & 63;
    int dm = tap >> 3, dn = tap & 7;
    const float R = 0.70710678118654752f;
    const float ct[8] = {1.f, R, 0.f, -R, -1.f, -R, 0.f, R};
    const float* fc = fp + c*40;
    float s = 0.f;
    #pragma unroll
    for (int u=0; u<8; u++){
        #pragma unroll
        for (int v=0; v<8; v++){
            float m1 = (v<=4) ? fc[u*5 + v]
                              : fc[((8-u)&7)*5 + (8-v)];
            int u2 = (8-u)&7, v2 = (8-v)&7;
            float m2 = (v2<=4) ? fc[u2*5 + v2]
                               : fc[((8-u2)&7)*5 + (8-v2)];
            float Ms = 0.5f*(m1+m2);
            s += Ms * ct[(u*dm + v*dn)&7];
        }
    }
    kk[c*64 + dm*8 + dn] = s * (1.0f/64.0f);
}

// ------------- K14b: per-patch circular conv + residual (in-place on d_out) -------------
__global__ __launch_bounds__(256) void k_patchconv_res(const float* __restrict__ y2,
        const float* __restrict__ kk, float* __restrict__ out){
    int idx = blockIdx.x*256 + threadIdx.x;
    if (idx >= BATCH*CDIM*LTOT) return;
    int l = idx & (LTOT-1); int bc = idx >> 14; int c = bc & (CDIM-1);
    int h = l >> 7, w = l & (WDIM-1);
    int hb = h>>3, hi = h&7, wb = w>>3, wi = w&7;
    const float* yb = y2 + (size_t)bc*LTOT + (hb*8)*WDIM + wb*8;
    const float* kc = kk + c*64;
    float acc = 0.f;
    #pragma unroll
    for (int m=0;m<8;m++){
        #pragma unroll
        for (int n=0;n<8;n++){
            acc += yb[m*WDIM + n] * kc[((hi-m)&7)*8 + ((wi-n)&7)];
        }
    }
    out[idx] += acc;
}

extern "C" void kernel_launch(void* const* d_in, const int* in_sizes, int n_in,
                              void* d_out, int out_size, void* d_ws, size_t ws_size,
                              hipStream_t stream){
    const float* x         = (const float*)d_in[0];
    const float* norm1_w   = (const float*)d_in[1];
    const float* norm1_b   = (const float*)d_in[2];
    const float* in_proj_w = (const float*)d_in[3];
    const float* conv2d_w  = (const float*)d_in[4];
    const float* conv2d_b  = (const float*)d_in[5];
    const float* x_proj_w  = (const float*)d_in[6];
    const float* x_conv_w  = (const float*)d_in[7];
    const float* x_conv_b  = (const float*)d_in[8];
    const float* dt_projs_w= (const float*)d_in[9];
    const float* dt_projs_b= (const float*)d_in[10];
    const float* A_logs    = (const float*)d_in[11];
    const float* Ds        = (const float*)d_in[12];
    const float* out_norm_w= (const float*)d_in[13];
    const float* out_norm_b= (const float*)d_in[14];
    const float* out_proj_w= (const float*)d_in[15];
    const float* norm2_w   = (const float*)d_in[16];
    const float* norm2_b   = (const float*)d_in[17];
    const float* pin_w     = (const float*)d_in[18];
    const float* dw_w      = (const float*)d_in[19];
    const float* fft_p     = (const float*)d_in[20];
    const float* pout_w    = (const float*)d_in[21];
    float* out = (float*)d_out;
    float* ws  = (float*)d_ws;

    float* xf    = ws + OFF_XF;
    float* z     = ws + OFF_Z;
    float* xin   = ws + OFF_XIN;
    float* xs    = ws + OFF_XS;
    float* xdbl0 = ws + OFF_XDBL0;
    float* xdbl1 = ws + OFF_XDBL1;
    float* PS    = ws + OFF_PS;
    float* Hinit = ws + OFF_HINIT;
    float* y     = ws + OFF_Y;
    float* h2    = ws + OFF_H2;
    float* g     = ws + OFF_G;
    float* y2    = ws + OFF_Y2;
    float* kk    = ws + OFF_KK;

    // ---- SS2D branch ----
    k_flip<<<(BATCH*CDIM*LTOT+255)/256, 256, 0, stream>>>(x, xf);
    k_ln_inproj<<<BATCH*(LTOT/64), 256, 0, stream>>>(xf, norm1_w, norm1_b, in_proj_w, xin, z);
    k_dwconv2d_gelu<<<(BATCH*DINNER*LTOT+255)/256, 256, 0, stream>>>(xin, conv2d_w, conv2d_b, xs);
    k_xproj<<<(BATCH*LTOT+255)/256, 256, 0, stream>>>(xs, x_proj_w, xdbl0);
    k_dwconv1d<<<(BATCH*CDBL*LTOT+255)/256, 256, 0, stream>>>(xdbl0, x_conv_w, x_conv_b, xdbl1);
    k_scan1<<<(BATCH*DINNER*LTOT+255)/256, 256, 0, stream>>>(xdbl1, xs, A_logs, dt_projs_w, dt_projs_b, PS);
    k_scan2<<<(BATCH*DINNER*DSTATE+255)/256, 256, 0, stream>>>(PS, Hinit);
    k_scan3<<<(BATCH*DINNER*LTOT+255)/256, 256, 0, stream>>>(xdbl1, xs, A_logs, dt_projs_w, dt_projs_b, Ds, Hinit, y);
    k_gate_out<<<BATCH*(LTOT/64), 256, 0, stream>>>(y, z, out_norm_w, out_norm_b, out_proj_w, xf, out);

    // ---- EDFFN branch (out currently holds x2) ----
    k_ln_pin<<<BATCH*(LTOT/64), 256, 0, stream>>>(out, norm2_w, norm2_b, pin_w, h2);
    k_dwconv_gate<<<(BATCH*NHID*LTOT+255)/256, 256, 0, stream>>>(h2, dw_w, g);
    k_pout<<<BATCH*(LTOT/64), 256, 0, stream>>>(g, pout_w, y2);
    k_fftker<<<(CDIM*64+255)/256, 256, 0, stream>>>(fft_p, kk);
    k_patchconv_res<<<(BATCH*CDIM*LTOT+255)/256, 256, 0, stream>>>(y2, kk, out);
}

// Round 4
// 460.355 us; speedup vs baseline: 5.8178x; 1.2765x over previous
//
#include <hip/hip_runtime.h>
#include <math.h>

#define BATCH   2
#define CDIM    64
#define DSTATE  8
#define DINNER  128
#define DTRANK  4
#define CDBL    20       // DTRANK + 2*DSTATE
#define HDIM    128
#define WDIM    128
#define LTOT    16384    // HDIM*WDIM
#define NHID    192      // HIDDEN
#define NC      256      // scan chunks
#define CHUNKL  64       // LTOT / NC

// ---- workspace offsets (floats) ----
static const size_t OFF_XF    = 0;            // 2*64*16384   = 2097152
static const size_t OFF_Z     = 2097152;      // (B,128,L)    = 4194304  (channel-major)
static const size_t OFF_XIN   = 6291456;      // (B,128,L)    = 4194304
static const size_t OFF_XS    = 10485760;     // (B,128,L)    = 4194304
static const size_t OFF_XDBL0 = 18874368;     // (B,20,L)     = 655360
static const size_t OFF_XDBL1 = 19529728;     // (B,20,L)     = 655360
static const size_t OFF_PS    = 20185088;     // 2*128*256*16 = 1048576
static const size_t OFF_HINIT = 21233664;     // 2*128*256*8  = 524288
static const size_t OFF_Y     = OFF_XIN;      // reuse xin
// EDFFN phase (reuses dead SS2D buffers)
static const size_t OFF_H2    = 0;            // (B,384,L)    = 12582912
static const size_t OFF_G     = 12582912;     // (B,192,L)    = 6291456
static const size_t OFF_Y2    = 18874368;     // (B,64,L)     = 2097152
static const size_t OFF_KK    = 21757952;     // 64*8*8       = 4096

__device__ __forceinline__ float gelu_exact(float x){
    return x * 0.5f * (1.0f + erff(x * 0.70710678118654752f));
}
__device__ __forceinline__ float softplus_f(float x){
    return (x > 20.0f) ? x : log1pf(expf(x));
}

// ---------------- K1: flip H,W ----------------
__global__ __launch_bounds__(256) void k_flip(const float* __restrict__ x, float* __restrict__ xf){
    int idx = blockIdx.x*256 + threadIdx.x;
    if (idx >= BATCH*CDIM*LTOT) return;
    int l = idx & (LTOT-1); int bc = idx >> 14;
    int h = l >> 7, w = l & (WDIM-1);
    xf[idx] = x[(size_t)bc*LTOT + (HDIM-1-h)*WDIM + (WDIM-1-w)];
}

// ------------- K2: wb_ln(norm1) + in_proj, LDS-tiled, output-split x4 -------------
// grid: BATCH * (LTOT/64) * 4.  Each block: 64 positions, 64 of 256 outputs.
__global__ __launch_bounds__(256) void k_ln_inproj(const float* __restrict__ xf,
        const float* __restrict__ nw, const float* __restrict__ nb,
        const float* __restrict__ Wp, float* __restrict__ xin, float* __restrict__ z){
    __shared__ float lx[CDIM][65];
    __shared__ float pr[4][64];
    __shared__ float rsA[64];
    int blk = blockIdx.x;
    int b = blk >> 10;
    int rem = blk & 1023;
    int l0 = (rem >> 2) << 6;
    int part = rem & 3;           // which 64-output slice
    int tid = threadIdx.x;
    for (int i=tid; i<CDIM*64; i+=256){
        int ch = i>>6, j = i&63;
        lx[ch][j] = xf[((size_t)b*CDIM+ch)*LTOT + l0 + j];
    }
    __syncthreads();
    {
        int pos = tid & 63, q = tid >> 6;
        float s = 0.f;
        for (int c=q*16; c<q*16+16; c++){ float v = lx[c][pos]; s += v*v; }
        pr[q][pos] = s;
    }
    __syncthreads();
    if (tid < 64){
        float t = pr[0][tid]+pr[1][tid]+pr[2][tid]+pr[3][tid];
        rsA[tid] = rsqrtf(t*(1.0f/CDIM) + 1e-6f);
    }
    __syncthreads();
    for (int i=tid; i<CDIM*64; i+=256){
        int ch = i>>6, j = i&63;
        lx[ch][j] = lx[ch][j]*rsA[j]*nw[ch] + nb[ch];
    }
    __syncthreads();
    int j = tid & 63;
    int grp = __builtin_amdgcn_readfirstlane(tid >> 6);   // wave-uniform -> scalar weight loads
    int o0 = part*64 + grp*16;
    float acc[16];
    #pragma unroll
    for (int oi=0;oi<16;oi++) acc[oi]=0.f;
    for (int cb=0; cb<8; cb++){
        float xv[8];
        #pragma unroll
        for (int cc=0;cc<8;cc++) xv[cc] = lx[cb*8+cc][j];
        #pragma unroll
        for (int oi=0;oi<16;oi++){
            const float* wr = Wp + (size_t)(o0+oi)*CDIM + cb*8;
            #pragma unroll
            for (int cc=0;cc<8;cc++) acc[oi] += xv[cc]*wr[cc];
        }
    }
    #pragma unroll
    for (int oi=0;oi<16;oi++){
        int o = o0+oi;
        float* dst = (o < DINNER) ? (xin + ((size_t)b*DINNER + o)*LTOT)
                                  : (z   + ((size_t)b*DINNER + (o-DINNER))*LTOT);
        dst[l0 + j] = acc[oi];
    }
}

// ------------- K3: depthwise conv2d 3x3 + gelu -------------
__global__ __launch_bounds__(256) void k_dwconv2d_gelu(const float* __restrict__ xin,
        const float* __restrict__ cw, const float* __restrict__ cb, float* __restrict__ xs){
    int idx = blockIdx.x*256 + threadIdx.x;
    if (idx >= BATCH*DINNER*LTOT) return;
    int l = idx & (LTOT-1); int bd = idx >> 14; int d = bd & (DINNER-1);
    int h = l >> 7, w = l & (WDIM-1);
    const float* base = xin + (size_t)bd*LTOT;
    float acc = cb[d];
    #pragma unroll
    for (int dh=-1; dh<=1; dh++){
        int hh = h+dh; if (hh<0||hh>=HDIM) continue;
        #pragma unroll
        for (int dw=-1; dw<=1; dw++){
            int ww = w+dw; if (ww<0||ww>=WDIM) continue;
            acc += base[hh*WDIM+ww] * cw[d*9 + (dh+1)*3 + (dw+1)];
        }
    }
    xs[idx] = gelu_exact(acc);
}

// ------------- K4: x_proj (128 -> 20) -------------
__global__ __launch_bounds__(256) void k_xproj(const float* __restrict__ xs,
        const float* __restrict__ Wx, float* __restrict__ xdbl_pre){
    int idx = blockIdx.x*256 + threadIdx.x;
    if (idx >= BATCH*LTOT) return;
    int b = idx >> 14, l = idx & (LTOT-1);
    float acc[CDBL];
    #pragma unroll
    for (int r=0;r<CDBL;r++) acc[r]=0.f;
    for (int d=0; d<DINNER; d++){
        float v = xs[((size_t)b*DINNER+d)*LTOT + l];
        #pragma unroll
        for (int r=0;r<CDBL;r++) acc[r] += v * Wx[r*DINNER+d];
    }
    #pragma unroll
    for (int r=0;r<CDBL;r++) xdbl_pre[((size_t)b*CDBL+r)*LTOT + l] = acc[r];
}

// ------------- K5: depthwise conv1d k=7 pad=3 + bias -------------
__global__ __launch_bounds__(256) void k_dwconv1d(const float* __restrict__ xp,
        const float* __restrict__ cw, const float* __restrict__ cb, float* __restrict__ xdbl){
    int idx = blockIdx.x*256 + threadIdx.x;
    if (idx >= BATCH*CDBL*LTOT) return;
    int l = idx & (LTOT-1); int br = idx >> 14; int r = br % CDBL;
    const float* base = xp + (size_t)br*LTOT;
    float acc = cb[r];
    #pragma unroll
    for (int k=0;k<7;k++){
        int t = l + k - 3;
        if (t>=0 && t<LTOT) acc += base[t]*cw[r*7+k];
    }
    xdbl[idx] = acc;
}

// ------------- K7: scan pass1 — intra-wave parallel scan, lane = timestep -------------
__global__ __launch_bounds__(256) void k_scan1(const float* __restrict__ xdbl,
        const float* __restrict__ xs, const float* __restrict__ A_logs,
        const float* __restrict__ dtw, const float* __restrict__ dtb,
        float* __restrict__ PS){
    int gtid = blockIdx.x*256 + threadIdx.x;
    int W = gtid >> 6;
    int lane = threadIdx.x & 63;
    int c = W & (NC-1);
    int bd = W >> 8;
    int d = bd & (DINNER-1);
    int b = bd >> 7;
    int l = c*CHUNKL + lane;
    const float* xb = xdbl + (size_t)b*CDBL*LTOT;
    float dtr = dtb[d];
    #pragma unroll
    for (int r=0;r<DTRANK;r++) dtr += xb[(size_t)r*LTOT + l] * dtw[d*DTRANK+r];
    float dt = softplus_f(dtr);
    float xv = xs[(size_t)bd*LTOT + l];
    float A[DSTATE], u[DSTATE];
    float dx = dt*xv;
    #pragma unroll
    for (int n=0;n<DSTATE;n++){
        A[n] = -expf(A_logs[d*DSTATE+n]);
        u[n] = dx * xb[(size_t)(DTRANK+n)*LTOT + l];
    }
    float cum = dt;
    #pragma unroll
    for (int k=1;k<64;k<<=1){
        float v = __shfl_up(cum, k);
        if (lane >= k) cum += v;
    }
    #pragma unroll
    for (int k=1;k<64;k<<=1){
        float cp = __shfl_up(cum, k);
        float up[DSTATE];
        #pragma unroll
        for (int n=0;n<DSTATE;n++) up[n] = __shfl_up(u[n], k);
        if (lane >= k){
            float dc = cum - cp;
            #pragma unroll
            for (int n=0;n<DSTATE;n++) u[n] += __expf(A[n]*dc) * up[n];
        }
    }
    if (lane == 63){
        float* ps = PS + (size_t)W*16;
        #pragma unroll
        for (int n=0;n<DSTATE;n++){ ps[n] = __expf(A[n]*cum); ps[8+n] = u[n]; }
    }
}

// ------------- K8: cross-chunk scan -------------
__global__ __launch_bounds__(256) void k_scan2(const float* __restrict__ PS, float* __restrict__ Hinit){
    int idx = blockIdx.x*256 + threadIdx.x;
    if (idx >= BATCH*DINNER*DSTATE) return;
    int n = idx & (DSTATE-1); int bd = idx >> 3;
    float h = 0.f;
    for (int c=0;c<NC;c++){
        Hinit[((size_t)bd*NC + c)*DSTATE + n] = h;
        const float* ps = PS + ((size_t)bd*NC + c)*16;
        h = ps[n]*h + ps[8+n];
    }
}

// ------------- K9: scan pass2 — replay with Hinit, emit y -------------
__global__ __launch_bounds__(256) void k_scan3(const float* __restrict__ xdbl,
        const float* __restrict__ xs, const float* __restrict__ A_logs,
        const float* __restrict__ dtw, const float* __restrict__ dtb,
        const float* __restrict__ Ds, const float* __restrict__ Hinit,
        float* __restrict__ y){
    int gtid = blockIdx.x*256 + threadIdx.x;
    int W = gtid >> 6;
    int lane = threadIdx.x & 63;
    int c = W & (NC-1);
    int bd = W >> 8;
    int d = bd & (DINNER-1);
    int b = bd >> 7;
    int l = c*CHUNKL + lane;
    const float* xb = xdbl + (size_t)b*CDBL*LTOT;
    float dtr = dtb[d];
    #pragma unroll
    for (int r=0;r<DTRANK;r++) dtr += xb[(size_t)r*LTOT + l] * dtw[d*DTRANK+r];
    float dt = softplus_f(dtr);
    float xv = xs[(size_t)bd*LTOT + l];
    float A[DSTATE], u[DSTATE];
    float dx = dt*xv;
    #pragma unroll
    for (int n=0;n<DSTATE;n++){
        A[n] = -expf(A_logs[d*DSTATE+n]);
        u[n] = dx * xb[(size_t)(DTRANK+n)*LTOT + l];
    }
    float cum = dt;
    #pragma unroll
    for (int k=1;k<64;k<<=1){
        float v = __shfl_up(cum, k);
        if (lane >= k) cum += v;
    }
    #pragma unroll
    for (int k=1;k<64;k<<=1){
        float cp = __shfl_up(cum, k);
        float up[DSTATE];
        #pragma unroll
        for (int n=0;n<DSTATE;n++) up[n] = __shfl_up(u[n], k);
        if (lane >= k){
            float dc = cum - cp;
            #pragma unroll
            for (int n=0;n<DSTATE;n++) u[n] += __expf(A[n]*dc) * up[n];
        }
    }
    const float* hi = Hinit + ((size_t)bd*NC + c)*DSTATE;
    float acc = Ds[d]*xv;
    #pragma unroll
    for (int n=0;n<DSTATE;n++){
        float Cv = xb[(size_t)(DTRANK+DSTATE+n)*LTOT + l];
        float h = u[n] + hi[n]*__expf(A[n]*cum);
        acc += h*Cv;
    }
    y[(size_t)bd*LTOT + l] = acc;
}

// ------------- K10: LN(y)*gelu(z) -> out_proj -> + xf, output-split x2 -------------
// grid: BATCH * (LTOT/64) * 2.  Each block: 64 positions, 32 of 64 outputs.
__global__ __launch_bounds__(256) void k_gate_out(const float* __restrict__ y,
        const float* __restrict__ z, const float* __restrict__ onw, const float* __restrict__ onb,
        const float* __restrict__ Wout, const float* __restrict__ xf, float* __restrict__ out){
    __shared__ float ly[DINNER][65];
    __shared__ float pr1[4][64], pr2[4][64];
    __shared__ float muA[64], rsA[64];
    int blk = blockIdx.x;
    int b = blk >> 9;
    int rem = blk & 511;
    int l0 = (rem >> 1) << 6;
    int part = rem & 1;
    int tid = threadIdx.x;
    for (int i=tid; i<DINNER*64; i+=256){
        int dd = i>>6, j = i&63;
        ly[dd][j] = y[((size_t)b*DINNER+dd)*LTOT + l0 + j];
    }
    __syncthreads();
    {
        int pos = tid & 63, q = tid >> 6;
        float s1=0.f, s2=0.f;
        for (int dd=q*32; dd<q*32+32; dd++){ float v = ly[dd][pos]; s1+=v; s2+=v*v; }
        pr1[q][pos]=s1; pr2[q][pos]=s2;
    }
    __syncthreads();
    if (tid < 64){
        float s1 = pr1[0][tid]+pr1[1][tid]+pr1[2][tid]+pr1[3][tid];
        float s2 = pr2[0][tid]+pr2[1][tid]+pr2[2][tid]+pr2[3][tid];
        float mu = s1*(1.0f/DINNER);
        float var = s2*(1.0f/DINNER) - mu*mu;
        muA[tid]=mu; rsA[tid]=rsqrtf(var + 1e-5f);
    }
    __syncthreads();
    for (int i=tid; i<DINNER*64; i+=256){
        int dd = i>>6, j = i&63;
        float zv = z[((size_t)b*DINNER+dd)*LTOT + l0 + j];
        ly[dd][j] = ((ly[dd][j]-muA[j])*rsA[j]*onw[dd] + onb[dd]) * gelu_exact(zv);
    }
    __syncthreads();
    int j = tid & 63;
    int grp = __builtin_amdgcn_readfirstlane(tid >> 6);
    int o0 = part*32 + grp*8;
    float acc[8];
    #pragma unroll
    for (int oi=0;oi<8;oi++) acc[oi]=0.f;
    for (int cb=0; cb<16; cb++){
        float xv[8];
        #pragma unroll
        for (int cc=0;cc<8;cc++) xv[cc] = ly[cb*8+cc][j];
        #pragma unroll
        for (int oi=0;oi<8;oi++){
            const float* wr = Wout + (size_t)(o0+oi)*DINNER + cb*8;
            #pragma unroll
            for (int cc=0;cc<8;cc++) acc[oi] += xv[cc]*wr[cc];
        }
    }
    #pragma unroll
    for (int oi=0;oi<8;oi++){
        size_t off = ((size_t)b*CDIM + o0+oi)*LTOT + l0 + j;
        out[off] = xf[off] + acc[oi];
    }
}

// ------------- K11: wb_ln(norm2) + pin (64 -> 384), output-split x4 -------------
// grid: BATCH * (LTOT/64) * 4.  Each block: 64 positions, 96 of 384 outputs.
__global__ __launch_bounds__(256) void k_ln_pin(const float* __restrict__ x2,
        const float* __restrict__ nw, const float* __restrict__ nb,
        const float* __restrict__ Wp, float* __restrict__ h2){
    __shared__ float lx[CDIM][65];
    __shared__ float pr[4][64];
    __shared__ float rsA[64];
    int blk = blockIdx.x;
    int b = blk >> 10;
    int rem = blk & 1023;
    int l0 = (rem >> 2) << 6;
    int part = rem & 3;
    int tid = threadIdx.x;
    for (int i=tid; i<CDIM*64; i+=256){
        int ch = i>>6, j = i&63;
        lx[ch][j] = x2[((size_t)b*CDIM+ch)*LTOT + l0 + j];
    }
    __syncthreads();
    {
        int pos = tid & 63, q = tid >> 6;
        float s = 0.f;
        for (int c=q*16; c<q*16+16; c++){ float v = lx[c][pos]; s += v*v; }
        pr[q][pos] = s;
    }
    __syncthreads();
    if (tid < 64){
        float t = pr[0][tid]+pr[1][tid]+pr[2][tid]+pr[3][tid];
        rsA[tid] = rsqrtf(t*(1.0f/CDIM) + 1e-6f);
    }
    __syncthreads();
    for (int i=tid; i<CDIM*64; i+=256){
        int ch = i>>6, j = i&63;
        lx[ch][j] = lx[ch][j]*rsA[j]*nw[ch] + nb[ch];
    }
    __syncthreads();
    int j = tid & 63;
    int grp = __builtin_amdgcn_readfirstlane(tid >> 6);
    int o0 = part*96 + grp*24;
    float acc[24];
    #pragma unroll
    for (int oi=0;oi<24;oi++) acc[oi]=0.f;
    for (int cb=0; cb<8; cb++){
        float xv[8];
        #pragma unroll
        for (int cc=0;cc<8;cc++) xv[cc] = lx[cb*8+cc][j];
        #pragma unroll
        for (int oi=0;oi<24;oi++){
            const float* wr = Wp + (size_t)(o0+oi)*CDIM + cb*8;
            #pragma unroll
            for (int cc=0;cc<8;cc++) acc[oi] += xv[cc]*wr[cc];
        }
    }
    #pragma unroll
    for (int oi=0;oi<24;oi++){
        h2[((size_t)b*2*NHID + o0+oi)*LTOT + l0 + j] = acc[oi];
    }
}

// ------------- K12: dwconv2d 3x3 (no bias) + gelu-gate -------------
__global__ __launch_bounds__(256) void k_dwconv_gate(const float* __restrict__ h2,
        const float* __restrict__ dww, float* __restrict__ g){
    int idx = blockIdx.x*256 + threadIdx.x;
    if (idx >= BATCH*NHID*LTOT) return;
    int l = idx & (LTOT-1); int bc = idx >> 14; int ch = bc % NHID; int b = bc / NHID;
    int h = l >> 7, w = l & (WDIM-1);
    const float* b1 = h2 + ((size_t)b*2*NHID + ch)*LTOT;
    const float* b2 = b1 + (size_t)NHID*LTOT;
    float a1=0.f, a2=0.f;
    #pragma unroll
    for (int dh=-1; dh<=1; dh++){
        int hh = h+dh; if (hh<0||hh>=HDIM) continue;
        #pragma unroll
        for (int dw=-1; dw<=1; dw++){
            int ww = w+dw; if (ww<0||ww>=WDIM) continue;
            int tap = (dh+1)*3 + (dw+1);
            a1 += b1[hh*WDIM+ww] * dww[ch*9 + tap];
            a2 += b2[hh*WDIM+ww] * dww[(ch+NHID)*9 + tap];
        }
    }
    g[idx] = gelu_exact(a1)*a2;
}

// ------------- K13: pout (192 -> 64), output-split x2 -------------
// grid: BATCH * (LTOT/64) * 2.  Each block: 64 positions, 32 of 64 outputs.
__global__ __launch_bounds__(256) void k_pout(const float* __restrict__ g,
        const float* __restrict__ Wp, float* __restrict__ y2){
    __shared__ float lg[NHID][65];
    int blk = blockIdx.x;
    int b = blk >> 9;
    int rem = blk & 511;
    int l0 = (rem >> 1) << 6;
    int part = rem & 1;
    int tid = threadIdx.x;
    for (int i=tid; i<NHID*64; i+=256){
        int c = i>>6, j = i&63;
        lg[c][j] = g[((size_t)b*NHID+c)*LTOT + l0 + j];
    }
    __syncthreads();
    int j = tid & 63;
    int grp = __builtin_amdgcn_readfirstlane(tid >> 6);
    int o0 = part*32 + grp*8;
    float acc[8];
    #pragma unroll
    for (int oi=0;oi<8;oi++) acc[oi]=0.f;
    for (int cb=0; cb<24; cb++){
        float xv[8];
        #pragma unroll
        for (int cc=0;cc<8;cc++) xv[cc] = lg[cb*8+cc][j];
        #pragma unroll
        for (int oi=0;oi<8;oi++){
            const float* wr = Wp + (size_t)(o0+oi)*NHID + cb*8;
            #pragma unroll
            for (int cc=0;cc<8;cc++) acc[oi] += xv[cc]*wr[cc];
        }
    }
    #pragma unroll
    for (int oi=0;oi<8;oi++){
        y2[((size_t)b*CDIM + o0+oi)*LTOT + l0 + j] = acc[oi];
    }
}

// ------------- K14a: build per-channel 8x8 circular kernel from fft_p -------------
__global__ __launch_bounds__(256) void k_fftker(const float* __restrict__ fp, float* __restrict__ kk){
    int idx = blockIdx.x*256 + threadIdx.x;
    if (idx >= CDIM*64) return;
    int c = idx >> 6, tap = idx & 63;
    int dm = tap >> 3, dn = tap & 7;
    const float R = 0.70710678118654752f;
    const float ct[8] = {1.f, R, 0.f, -R, -1.f, -R, 0.f, R};
    const float* fc = fp + c*40;
    float s = 0.f;
    #pragma unroll
    for (int u=0; u<8; u++){
        #pragma unroll
        for (int v=0; v<8; v++){
            float m1 = (v<=4) ? fc[u*5 + v]
                              : fc[((8-u)&7)*5 + (8-v)];
            int u2 = (8-u)&7, v2 = (8-v)&7;
            float m2 = (v2<=4) ? fc[u2*5 + v2]
                               : fc[((8-u2)&7)*5 + (8-v2)];
            float Ms = 0.5f*(m1+m2);
            s += Ms * ct[(u*dm + v*dn)&7];
        }
    }
    kk[c*64 + dm*8 + dn] = s * (1.0f/64.0f);
}

// ------------- K14b: per-patch circular conv + residual (in-place on d_out) -------------
__global__ __launch_bounds__(256) void k_patchconv_res(const float* __restrict__ y2,
        const float* __restrict__ kk, float* __restrict__ out){
    int idx = blockIdx.x*256 + threadIdx.x;
    if (idx >= BATCH*CDIM*LTOT) return;
    int l = idx & (LTOT-1); int bc = idx >> 14; int c = bc & (CDIM-1);
    int h = l >> 7, w = l & (WDIM-1);
    int hb = h>>3, hi = h&7, wb = w>>3, wi = w&7;
    const float* yb = y2 + (size_t)bc*LTOT + (hb*8)*WDIM + wb*8;
    const float* kc = kk + c*64;
    float acc = 0.f;
    #pragma unroll
    for (int m=0;m<8;m++){
        #pragma unroll
        for (int n=0;n<8;n++){
            acc += yb[m*WDIM + n] * kc[((hi-m)&7)*8 + ((wi-n)&7)];
        }
    }
    out[idx] += acc;
}

extern "C" void kernel_launch(void* const* d_in, const int* in_sizes, int n_in,
                              void* d_out, int out_size, void* d_ws, size_t ws_size,
                              hipStream_t stream){
    const float* x         = (const float*)d_in[0];
    const float* norm1_w   = (const float*)d_in[1];
    const float* norm1_b   = (const float*)d_in[2];
    const float* in_proj_w = (const float*)d_in[3];
    const float* conv2d_w  = (const float*)d_in[4];
    const float* conv2d_b  = (const float*)d_in[5];
    const float* x_proj_w  = (const float*)d_in[6];
    const float* x_conv_w  = (const float*)d_in[7];
    const float* x_conv_b  = (const float*)d_in[8];
    const float* dt_projs_w= (const float*)d_in[9];
    const float* dt_projs_b= (const float*)d_in[10];
    const float* A_logs    = (const float*)d_in[11];
    const float* Ds        = (const float*)d_in[12];
    const float* out_norm_w= (const float*)d_in[13];
    const float* out_norm_b= (const float*)d_in[14];
    const float* out_proj_w= (const float*)d_in[15];
    const float* norm2_w   = (const float*)d_in[16];
    const float* norm2_b   = (const float*)d_in[17];
    const float* pin_w     = (const float*)d_in[18];
    const float* dw_w      = (const float*)d_in[19];
    const float* fft_p     = (const float*)d_in[20];
    const float* pout_w    = (const float*)d_in[21];
    float* out = (float*)d_out;
    float* ws  = (float*)d_ws;

    float* xf    = ws + OFF_XF;
    float* z     = ws + OFF_Z;
    float* xin   = ws + OFF_XIN;
    float* xs    = ws + OFF_XS;
    float* xdbl0 = ws + OFF_XDBL0;
    float* xdbl1 = ws + OFF_XDBL1;
    float* PS    = ws + OFF_PS;
    float* Hinit = ws + OFF_HINIT;
    float* y     = ws + OFF_Y;
    float* h2    = ws + OFF_H2;
    float* g     = ws + OFF_G;
    float* y2    = ws + OFF_Y2;
    float* kk    = ws + OFF_KK;

    // ---- SS2D branch ----
    k_flip<<<(BATCH*CDIM*LTOT+255)/256, 256, 0, stream>>>(x, xf);
    k_ln_inproj<<<BATCH*(LTOT/64)*4, 256, 0, stream>>>(xf, norm1_w, norm1_b, in_proj_w, xin, z);
    k_dwconv2d_gelu<<<(BATCH*DINNER*LTOT+255)/256, 256, 0, stream>>>(xin, conv2d_w, conv2d_b, xs);
    k_xproj<<<(BATCH*LTOT+255)/256, 256, 0, stream>>>(xs, x_proj_w, xdbl0);
    k_dwconv1d<<<(BATCH*CDBL*LTOT+255)/256, 256, 0, stream>>>(xdbl0, x_conv_w, x_conv_b, xdbl1);
    k_scan1<<<(BATCH*DINNER*LTOT+255)/256, 256, 0, stream>>>(xdbl1, xs, A_logs, dt_projs_w, dt_projs_b, PS);
    k_scan2<<<(BATCH*DINNER*DSTATE+255)/256, 256, 0, stream>>>(PS, Hinit);
    k_scan3<<<(BATCH*DINNER*LTOT+255)/256, 256, 0, stream>>>(xdbl1, xs, A_logs, dt_projs_w, dt_projs_b, Ds, Hinit, y);
    k_gate_out<<<BATCH*(LTOT/64)*2, 256, 0, stream>>>(y, z, out_norm_w, out_norm_b, out_proj_w, xf, out);

    // ---- EDFFN branch (out currently holds x2) ----
    k_ln_pin<<<BATCH*(LTOT/64)*4, 256, 0, stream>>>(out, norm2_w, norm2_b, pin_w, h2);
    k_dwconv_gate<<<(BATCH*NHID*LTOT+255)/256, 256, 0, stream>>>(h2, dw_w, g);
    k_pout<<<BATCH*(LTOT/64)*2, 256, 0, stream>>>(g, pout_w, y2);
    k_fftker<<<(CDIM*64+255)/256, 256, 0, stream>>>(fft_p, kk);
    k_patchconv_res<<<(BATCH*CDIM*LTOT+255)/256, 256, 0, stream>>>(y2, kk, out);
}

// Round 5
// 397.037 us; speedup vs baseline: 6.7456x; 1.1595x over previous
//
#include <hip/hip_runtime.h>
#include <math.h>

#define BATCH   2
#define CDIM    64
#define DSTATE  8
#define DINNER  128
#define DTRANK  4
#define CDBL    20       // DTRANK + 2*DSTATE
#define HDIM    128
#define WDIM    128
#define LTOT    16384    // HDIM*WDIM
#define NHID    192      // HIDDEN

// ---- workspace offsets (floats) ----
static const size_t OFF_XF    = 0;            // 2*64*16384   = 2097152
static const size_t OFF_Z     = 2097152;      // (B,128,L)    = 4194304  (channel-major)
static const size_t OFF_XIN   = 6291456;      // (B,128,L)    = 4194304
static const size_t OFF_XS    = 10485760;     // (B,128,L)    = 4194304
static const size_t OFF_XDBL0 = 18874368;     // (B,20,L)     = 655360
static const size_t OFF_XDBL1 = 19529728;     // (B,20,L)     = 655360
static const size_t OFF_Y     = OFF_XIN;      // reuse xin
// EDFFN phase (reuses dead SS2D buffers)
static const size_t OFF_H2    = 0;            // (B,384,L)    = 12582912
static const size_t OFF_G     = 12582912;     // (B,192,L)    = 6291456
static const size_t OFF_Y2    = 18874368;     // (B,64,L)     = 2097152
static const size_t OFF_KK    = 21757952;     // 64*8*8       = 4096

__device__ __forceinline__ float gelu_exact(float x){
    return x * 0.5f * (1.0f + erff(x * 0.70710678118654752f));
}
__device__ __forceinline__ float softplus_f(float x){
    return (x > 20.0f) ? x : log1pf(expf(x));
}

// ---------------- K1: flip H,W ----------------
__global__ __launch_bounds__(256) void k_flip(const float* __restrict__ x, float* __restrict__ xf){
    int idx = blockIdx.x*256 + threadIdx.x;
    if (idx >= BATCH*CDIM*LTOT) return;
    int l = idx & (LTOT-1); int bc = idx >> 14;
    int h = l >> 7, w = l & (WDIM-1);
    xf[idx] = x[(size_t)bc*LTOT + (HDIM-1-h)*WDIM + (WDIM-1-w)];
}

// ------------- K2: wb_ln(norm1) + in_proj, LDS-tiled, output-split x4 -------------
__global__ __launch_bounds__(256) void k_ln_inproj(const float* __restrict__ xf,
        const float* __restrict__ nw, const float* __restrict__ nb,
        const float* __restrict__ Wp, float* __restrict__ xin, float* __restrict__ z){
    __shared__ float lx[CDIM][65];
    __shared__ float pr[4][64];
    __shared__ float rsA[64];
    int blk = blockIdx.x;
    int b = blk >> 10;
    int rem = blk & 1023;
    int l0 = (rem >> 2) << 6;
    int part = rem & 3;           // which 64-output slice
    int tid = threadIdx.x;
    for (int i=tid; i<CDIM*64; i+=256){
        int ch = i>>6, j = i&63;
        lx[ch][j] = xf[((size_t)b*CDIM+ch)*LTOT + l0 + j];
    }
    __syncthreads();
    {
        int pos = tid & 63, q = tid >> 6;
        float s = 0.f;
        for (int c=q*16; c<q*16+16; c++){ float v = lx[c][pos]; s += v*v; }
        pr[q][pos] = s;
    }
    __syncthreads();
    if (tid < 64){
        float t = pr[0][tid]+pr[1][tid]+pr[2][tid]+pr[3][tid];
        rsA[tid] = rsqrtf(t*(1.0f/CDIM) + 1e-6f);
    }
    __syncthreads();
    for (int i=tid; i<CDIM*64; i+=256){
        int ch = i>>6, j = i&63;
        lx[ch][j] = lx[ch][j]*rsA[j]*nw[ch] + nb[ch];
    }
    __syncthreads();
    int j = tid & 63;
    int grp = __builtin_amdgcn_readfirstlane(tid >> 6);   // wave-uniform -> scalar weight loads
    int o0 = part*64 + grp*16;
    float acc[16];
    #pragma unroll
    for (int oi=0;oi<16;oi++) acc[oi]=0.f;
    for (int cb=0; cb<8; cb++){
        float xv[8];
        #pragma unroll
        for (int cc=0;cc<8;cc++) xv[cc] = lx[cb*8+cc][j];
        #pragma unroll
        for (int oi=0;oi<16;oi++){
            const float* wr = Wp + (size_t)(o0+oi)*CDIM + cb*8;
            #pragma unroll
            for (int cc=0;cc<8;cc++) acc[oi] += xv[cc]*wr[cc];
        }
    }
    #pragma unroll
    for (int oi=0;oi<16;oi++){
        int o = o0+oi;
        float* dst = (o < DINNER) ? (xin + ((size_t)b*DINNER + o)*LTOT)
                                  : (z   + ((size_t)b*DINNER + (o-DINNER))*LTOT);
        dst[l0 + j] = acc[oi];
    }
}

// ------------- K3: depthwise conv2d 3x3 + gelu -------------
__global__ __launch_bounds__(256) void k_dwconv2d_gelu(const float* __restrict__ xin,
        const float* __restrict__ cw, const float* __restrict__ cb, float* __restrict__ xs){
    int idx = blockIdx.x*256 + threadIdx.x;
    if (idx >= BATCH*DINNER*LTOT) return;
    int l = idx & (LTOT-1); int bd = idx >> 14; int d = bd & (DINNER-1);
    int h = l >> 7, w = l & (WDIM-1);
    const float* base = xin + (size_t)bd*LTOT;
    float acc = cb[d];
    #pragma unroll
    for (int dh=-1; dh<=1; dh++){
        int hh = h+dh; if (hh<0||hh>=HDIM) continue;
        #pragma unroll
        for (int dw=-1; dw<=1; dw++){
            int ww = w+dw; if (ww<0||ww>=WDIM) continue;
            acc += base[hh*WDIM+ww] * cw[d*9 + (dh+1)*3 + (dw+1)];
        }
    }
    xs[idx] = gelu_exact(acc);
}

// ------------- K4: x_proj (128 -> 20) -------------
__global__ __launch_bounds__(256) void k_xproj(const float* __restrict__ xs,
        const float* __restrict__ Wx, float* __restrict__ xdbl_pre){
    int idx = blockIdx.x*256 + threadIdx.x;
    if (idx >= BATCH*LTOT) return;
    int b = idx >> 14, l = idx & (LTOT-1);
    float acc[CDBL];
    #pragma unroll
    for (int r=0;r<CDBL;r++) acc[r]=0.f;
    for (int d=0; d<DINNER; d++){
        float v = xs[((size_t)b*DINNER+d)*LTOT + l];
        #pragma unroll
        for (int r=0;r<CDBL;r++) acc[r] += v * Wx[r*DINNER+d];
    }
    #pragma unroll
    for (int r=0;r<CDBL;r++) xdbl_pre[((size_t)b*CDBL+r)*LTOT + l] = acc[r];
}

// ------------- K5: depthwise conv1d k=7 pad=3 + bias -------------
__global__ __launch_bounds__(256) void k_dwconv1d(const float* __restrict__ xp,
        const float* __restrict__ cw, const float* __restrict__ cb, float* __restrict__ xdbl){
    int idx = blockIdx.x*256 + threadIdx.x;
    if (idx >= BATCH*CDBL*LTOT) return;
    int l = idx & (LTOT-1); int br = idx >> 14; int r = br % CDBL;
    const float* base = xp + (size_t)br*LTOT;
    float acc = cb[r];
    #pragma unroll
    for (int k=0;k<7;k++){
        int t = l + k - 3;
        if (t>=0 && t<LTOT) acc += base[t]*cw[r*7+k];
    }
    xdbl[idx] = acc;
}

// ------------- K7: FUSED selective scan — one block per (b,d) row -------------
// 1024 threads = 16 wave-chunks of 64; 16 iterations cover L=16384.
// Per wave-chunk: h_t = ep_t*(h_in + W_t), ep_t = exp(A*cum_t),
//   W_t = prefix( u_t * exp(-A*cum_t) ).  Wave summaries (P,S) composed
//   across the 16 waves by wave 0 (8 lanes), carry kept in registers.
__global__ __launch_bounds__(1024) void k_scan_fused(const float* __restrict__ xdbl,
        const float* __restrict__ xs, const float* __restrict__ A_logs,
        const float* __restrict__ dtw, const float* __restrict__ dtb,
        const float* __restrict__ Ds, float* __restrict__ y){
    __shared__ float PSp[16][8];   // per-wave P
    __shared__ float PSs[16][8];   // per-wave S
    __shared__ float HIN[16][8];   // per-wave incoming state
    int bd = blockIdx.x;           // 0 .. 255
    int d  = bd & (DINNER-1);
    int b  = bd >> 7;
    int tid = threadIdx.x;
    int lane = tid & 63;
    int wv = tid >> 6;             // 0..15
    const float* xb = xdbl + (size_t)b*CDBL*LTOT;
    const float* xrow = xs + (size_t)bd*LTOT;
    float* yrow = y + (size_t)bd*LTOT;
    float A[DSTATE];
    #pragma unroll
    for (int n=0;n<DSTATE;n++) A[n] = -expf(A_logs[d*DSTATE+n]);
    float w0=dtw[d*DTRANK], w1=dtw[d*DTRANK+1], w2=dtw[d*DTRANK+2], w3=dtw[d*DTRANK+3];
    float dtbd = dtb[d];
    float Dd = Ds[d];
    float car[DSTATE];             // live only in wave0 lanes 0..7
    #pragma unroll
    for (int n=0;n<DSTATE;n++) car[n]=0.f;

    for (int it=0; it<16; it++){
        int l = it*1024 + tid;
        // ---- loads ----
        float dtr = dtbd + xb[l]*w0 + xb[LTOT+l]*w1 + xb[2*LTOT+l]*w2 + xb[3*LTOT+l]*w3;
        float dt = softplus_f(dtr);
        float xv = xrow[l];
        float Bv[DSTATE], Cv[DSTATE];
        #pragma unroll
        for (int n=0;n<DSTATE;n++){
            Bv[n] = xb[(size_t)(DTRANK+n)*LTOT + l];
            Cv[n] = xb[(size_t)(DTRANK+DSTATE+n)*LTOT + l];
        }
        float dx = dt*xv;
        // ---- cum = inclusive prefix of dt within wave ----
        float cum = dt;
        #pragma unroll
        for (int k=1;k<64;k<<=1){
            float v = __shfl_up(cum, k);
            if (lane >= k) cum += v;
        }
        // ---- normalized increments + prefix sums ----
        float ep[DSTATE], W[DSTATE];
        #pragma unroll
        for (int n=0;n<DSTATE;n++){
            float q = -A[n]*cum;                       // >= 0
            float iv = __expf(fminf(q, 85.f));          // exp(-A*cum), clamped guard
            ep[n] = __expf(A[n]*cum);                   // exp(A*cum) <= 1
            W[n]  = dx*Bv[n]*iv;
        }
        #pragma unroll
        for (int k=1;k<64;k<<=1){
            float up[DSTATE];
            #pragma unroll
            for (int n=0;n<DSTATE;n++) up[n] = __shfl_up(W[n], k);
            if (lane >= k){
                #pragma unroll
                for (int n=0;n<DSTATE;n++) W[n] += up[n];
            }
        }
        // ---- wave summary (P,S) ----
        float pre[DSTATE];
        #pragma unroll
        for (int n=0;n<DSTATE;n++){
            pre[n] = ep[n]*W[n];
            float Pn = __shfl(ep[n], 63);
            float Sn = __shfl(pre[n], 63);
            if (lane == 0){ PSp[wv][n] = Pn; PSs[wv][n] = Sn; }
        }
        __syncthreads();
        // ---- wave 0 composes across the 16 waves ----
        if (wv == 0 && lane < DSTATE){
            int n = lane;
            float h = car[n];
            #pragma unroll
            for (int w=0; w<16; w++){
                HIN[w][n] = h;
                h = PSp[w][n]*h + PSs[w][n];
            }
            car[n] = h;
        }
        __syncthreads();
        // ---- finalize y ----
        float acc = Dd*xv;
        #pragma unroll
        for (int n=0;n<DSTATE;n++){
            float h = pre[n] + ep[n]*HIN[wv][n];
            acc += h*Cv[n];
        }
        yrow[l] = acc;
        __syncthreads();   // protect PSp/PSs/HIN reuse next iteration
    }
}

// ------------- K10: LN(y)*gelu(z) -> out_proj -> + xf, output-split x2 -------------
__global__ __launch_bounds__(256) void k_gate_out(const float* __restrict__ y,
        const float* __restrict__ z, const float* __restrict__ onw, const float* __restrict__ onb,
        const float* __restrict__ Wout, const float* __restrict__ xf, float* __restrict__ out){
    __shared__ float ly[DINNER][65];
    __shared__ float pr1[4][64], pr2[4][64];
    __shared__ float muA[64], rsA[64];
    int blk = blockIdx.x;
    int b = blk >> 9;
    int rem = blk & 511;
    int l0 = (rem >> 1) << 6;
    int part = rem & 1;
    int tid = threadIdx.x;
    for (int i=tid; i<DINNER*64; i+=256){
        int dd = i>>6, j = i&63;
        ly[dd][j] = y[((size_t)b*DINNER+dd)*LTOT + l0 + j];
    }
    __syncthreads();
    {
        int pos = tid & 63, q = tid >> 6;
        float s1=0.f, s2=0.f;
        for (int dd=q*32; dd<q*32+32; dd++){ float v = ly[dd][pos]; s1+=v; s2+=v*v; }
        pr1[q][pos]=s1; pr2[q][pos]=s2;
    }
    __syncthreads();
    if (tid < 64){
        float s1 = pr1[0][tid]+pr1[1][tid]+pr1[2][tid]+pr1[3][tid];
        float s2 = pr2[0][tid]+pr2[1][tid]+pr2[2][tid]+pr2[3][tid];
        float mu = s1*(1.0f/DINNER);
        float var = s2*(1.0f/DINNER) - mu*mu;
        muA[tid]=mu; rsA[tid]=rsqrtf(var + 1e-5f);
    }
    __syncthreads();
    for (int i=tid; i<DINNER*64; i+=256){
        int dd = i>>6, j = i&63;
        float zv = z[((size_t)b*DINNER+dd)*LTOT + l0 + j];
        ly[dd][j] = ((ly[dd][j]-muA[j])*rsA[j]*onw[dd] + onb[dd]) * gelu_exact(zv);
    }
    __syncthreads();
    int j = tid & 63;
    int grp = __builtin_amdgcn_readfirstlane(tid >> 6);
    int o0 = part*32 + grp*8;
    float acc[8];
    #pragma unroll
    for (int oi=0;oi<8;oi++) acc[oi]=0.f;
    for (int cb=0; cb<16; cb++){
        float xv[8];
        #pragma unroll
        for (int cc=0;cc<8;cc++) xv[cc] = ly[cb*8+cc][j];
        #pragma unroll
        for (int oi=0;oi<8;oi++){
            const float* wr = Wout + (size_t)(o0+oi)*DINNER + cb*8;
            #pragma unroll
            for (int cc=0;cc<8;cc++) acc[oi] += xv[cc]*wr[cc];
        }
    }
    #pragma unroll
    for (int oi=0;oi<8;oi++){
        size_t off = ((size_t)b*CDIM + o0+oi)*LTOT + l0 + j;
        out[off] = xf[off] + acc[oi];
    }
}

// ------------- K11: wb_ln(norm2) + pin (64 -> 384), output-split x4 -------------
__global__ __launch_bounds__(256) void k_ln_pin(const float* __restrict__ x2,
        const float* __restrict__ nw, const float* __restrict__ nb,
        const float* __restrict__ Wp, float* __restrict__ h2){
    __shared__ float lx[CDIM][65];
    __shared__ float pr[4][64];
    __shared__ float rsA[64];
    int blk = blockIdx.x;
    int b = blk >> 10;
    int rem = blk & 1023;
    int l0 = (rem >> 2) << 6;
    int part = rem & 3;
    int tid = threadIdx.x;
    for (int i=tid; i<CDIM*64; i+=256){
        int ch = i>>6, j = i&63;
        lx[ch][j] = x2[((size_t)b*CDIM+ch)*LTOT + l0 + j];
    }
    __syncthreads();
    {
        int pos = tid & 63, q = tid >> 6;
        float s = 0.f;
        for (int c=q*16; c<q*16+16; c++){ float v = lx[c][pos]; s += v*v; }
        pr[q][pos] = s;
    }
    __syncthreads();
    if (tid < 64){
        float t = pr[0][tid]+pr[1][tid]+pr[2][tid]+pr[3][tid];
        rsA[tid] = rsqrtf(t*(1.0f/CDIM) + 1e-6f);
    }
    __syncthreads();
    for (int i=tid; i<CDIM*64; i+=256){
        int ch = i>>6, j = i&63;
        lx[ch][j] = lx[ch][j]*rsA[j]*nw[ch] + nb[ch];
    }
    __syncthreads();
    int j = tid & 63;
    int grp = __builtin_amdgcn_readfirstlane(tid >> 6);
    int o0 = part*96 + grp*24;
    float acc[24];
    #pragma unroll
    for (int oi=0;oi<24;oi++) acc[oi]=0.f;
    for (int cb=0; cb<8; cb++){
        float xv[8];
        #pragma unroll
        for (int cc=0;cc<8;cc++) xv[cc] = lx[cb*8+cc][j];
        #pragma unroll
        for (int oi=0;oi<24;oi++){
            const float* wr = Wp + (size_t)(o0+oi)*CDIM + cb*8;
            #pragma unroll
            for (int cc=0;cc<8;cc++) acc[oi] += xv[cc]*wr[cc];
        }
    }
    #pragma unroll
    for (int oi=0;oi<24;oi++){
        h2[((size_t)b*2*NHID + o0+oi)*LTOT + l0 + j] = acc[oi];
    }
}

// ------------- K12: dwconv2d 3x3 (no bias) + gelu-gate -------------
__global__ __launch_bounds__(256) void k_dwconv_gate(const float* __restrict__ h2,
        const float* __restrict__ dww, float* __restrict__ g){
    int idx = blockIdx.x*256 + threadIdx.x;
    if (idx >= BATCH*NHID*LTOT) return;
    int l = idx & (LTOT-1); int bc = idx >> 14; int ch = bc % NHID; int b = bc / NHID;
    int h = l >> 7, w = l & (WDIM-1);
    const float* b1 = h2 + ((size_t)b*2*NHID + ch)*LTOT;
    const float* b2 = b1 + (size_t)NHID*LTOT;
    float a1=0.f, a2=0.f;
    #pragma unroll
    for (int dh=-1; dh<=1; dh++){
        int hh = h+dh; if (hh<0||hh>=HDIM) continue;
        #pragma unroll
        for (int dw=-1; dw<=1; dw++){
            int ww = w+dw; if (ww<0||ww>=WDIM) continue;
            int tap = (dh+1)*3 + (dw+1);
            a1 += b1[hh*WDIM+ww] * dww[ch*9 + tap];
            a2 += b2[hh*WDIM+ww] * dww[(ch+NHID)*9 + tap];
        }
    }
    g[idx] = gelu_exact(a1)*a2;
}

// ------------- K13: pout (192 -> 64), output-split x2 -------------
__global__ __launch_bounds__(256) void k_pout(const float* __restrict__ g,
        const float* __restrict__ Wp, float* __restrict__ y2){
    __shared__ float lg[NHID][65];
    int blk = blockIdx.x;
    int b = blk >> 9;
    int rem = blk & 511;
    int l0 = (rem >> 1) << 6;
    int part = rem & 1;
    int tid = threadIdx.x;
    for (int i=tid; i<NHID*64; i+=256){
        int c = i>>6, j = i&63;
        lg[c][j] = g[((size_t)b*NHID+c)*LTOT + l0 + j];
    }
    __syncthreads();
    int j = tid & 63;
    int grp = __builtin_amdgcn_readfirstlane(tid >> 6);
    int o0 = part*32 + grp*8;
    float acc[8];
    #pragma unroll
    for (int oi=0;oi<8;oi++) acc[oi]=0.f;
    for (int cb=0; cb<24; cb++){
        float xv[8];
        #pragma unroll
        for (int cc=0;cc<8;cc++) xv[cc] = lg[cb*8+cc][j];
        #pragma unroll
        for (int oi=0;oi<8;oi++){
            const float* wr = Wp + (size_t)(o0+oi)*NHID + cb*8;
            #pragma unroll
            for (int cc=0;cc<8;cc++) acc[oi] += xv[cc]*wr[cc];
        }
    }
    #pragma unroll
    for (int oi=0;oi<8;oi++){
        y2[((size_t)b*CDIM + o0+oi)*LTOT + l0 + j] = acc[oi];
    }
}

// ------------- K14a: build per-channel 8x8 circular kernel from fft_p -------------
__global__ __launch_bounds__(256) void k_fftker(const float* __restrict__ fp, float* __restrict__ kk){
    int idx = blockIdx.x*256 + threadIdx.x;
    if (idx >= CDIM*64) return;
    int c = idx >> 6, tap = idx & 63;
    int dm = tap >> 3, dn = tap & 7;
    const float R = 0.70710678118654752f;
    const float ct[8] = {1.f, R, 0.f, -R, -1.f, -R, 0.f, R};
    const float* fc = fp + c*40;
    float s = 0.f;
    #pragma unroll
    for (int u=0; u<8; u++){
        #pragma unroll
        for (int v=0; v<8; v++){
            float m1 = (v<=4) ? fc[u*5 + v]
                              : fc[((8-u)&7)*5 + (8-v)];
            int u2 = (8-u)&7, v2 = (8-v)&7;
            float m2 = (v2<=4) ? fc[u2*5 + v2]
                               : fc[((8-u2)&7)*5 + (8-v2)];
            float Ms = 0.5f*(m1+m2);
            s += Ms * ct[(u*dm + v*dn)&7];
        }
    }
    kk[c*64 + dm*8 + dn] = s * (1.0f/64.0f);
}

// ------------- K14b: per-patch circular conv + residual (in-place on d_out) -------------
__global__ __launch_bounds__(256) void k_patchconv_res(const float* __restrict__ y2,
        const float* __restrict__ kk, float* __restrict__ out){
    int idx = blockIdx.x*256 + threadIdx.x;
    if (idx >= BATCH*CDIM*LTOT) return;
    int l = idx & (LTOT-1); int bc = idx >> 14; int c = bc & (CDIM-1);
    int h = l >> 7, w = l & (WDIM-1);
    int hb = h>>3, hi = h&7, wb = w>>3, wi = w&7;
    const float* yb = y2 + (size_t)bc*LTOT + (hb*8)*WDIM + wb*8;
    const float* kc = kk + c*64;
    float acc = 0.f;
    #pragma unroll
    for (int m=0;m<8;m++){
        #pragma unroll
        for (int n=0;n<8;n++){
            acc += yb[m*WDIM + n] * kc[((hi-m)&7)*8 + ((wi-n)&7)];
        }
    }
    out[idx] += acc;
}

extern "C" void kernel_launch(void* const* d_in, const int* in_sizes, int n_in,
                              void* d_out, int out_size, void* d_ws, size_t ws_size,
                              hipStream_t stream){
    const float* x         = (const float*)d_in[0];
    const float* norm1_w   = (const float*)d_in[1];
    const float* norm1_b   = (const float*)d_in[2];
    const float* in_proj_w = (const float*)d_in[3];
    const float* conv2d_w  = (const float*)d_in[4];
    const float* conv2d_b  = (const float*)d_in[5];
    const float* x_proj_w  = (const float*)d_in[6];
    const float* x_conv_w  = (const float*)d_in[7];
    const float* x_conv_b  = (const float*)d_in[8];
    const float* dt_projs_w= (const float*)d_in[9];
    const float* dt_projs_b= (const float*)d_in[10];
    const float* A_logs    = (const float*)d_in[11];
    const float* Ds        = (const float*)d_in[12];
    const float* out_norm_w= (const float*)d_in[13];
    const float* out_norm_b= (const float*)d_in[14];
    const float* out_proj_w= (const float*)d_in[15];
    const float* norm2_w   = (const float*)d_in[16];
    const float* norm2_b   = (const float*)d_in[17];
    const float* pin_w     = (const float*)d_in[18];
    const float* dw_w      = (const float*)d_in[19];
    const float* fft_p     = (const float*)d_in[20];
    const float* pout_w    = (const float*)d_in[21];
    float* out = (float*)d_out;
    float* ws  = (float*)d_ws;

    float* xf    = ws + OFF_XF;
    float* z     = ws + OFF_Z;
    float* xin   = ws + OFF_XIN;
    float* xs    = ws + OFF_XS;
    float* xdbl0 = ws + OFF_XDBL0;
    float* xdbl1 = ws + OFF_XDBL1;
    float* y     = ws + OFF_Y;
    float* h2    = ws + OFF_H2;
    float* g     = ws + OFF_G;
    float* y2    = ws + OFF_Y2;
    float* kk    = ws + OFF_KK;

    // ---- SS2D branch ----
    k_flip<<<(BATCH*CDIM*LTOT+255)/256, 256, 0, stream>>>(x, xf);
    k_ln_inproj<<<BATCH*(LTOT/64)*4, 256, 0, stream>>>(xf, norm1_w, norm1_b, in_proj_w, xin, z);
    k_dwconv2d_gelu<<<(BATCH*DINNER*LTOT+255)/256, 256, 0, stream>>>(xin, conv2d_w, conv2d_b, xs);
    k_xproj<<<(BATCH*LTOT+255)/256, 256, 0, stream>>>(xs, x_proj_w, xdbl0);
    k_dwconv1d<<<(BATCH*CDBL*LTOT+255)/256, 256, 0, stream>>>(xdbl0, x_conv_w, x_conv_b, xdbl1);
    k_scan_fused<<<BATCH*DINNER, 1024, 0, stream>>>(xdbl1, xs, A_logs, dt_projs_w, dt_projs_b, Ds, y);
    k_gate_out<<<BATCH*(LTOT/64)*2, 256, 0, stream>>>(y, z, out_norm_w, out_norm_b, out_proj_w, xf, out);

    // ---- EDFFN branch (out currently holds x2) ----
    k_ln_pin<<<BATCH*(LTOT/64)*4, 256, 0, stream>>>(out, norm2_w, norm2_b, pin_w, h2);
    k_dwconv_gate<<<(BATCH*NHID*LTOT+255)/256, 256, 0, stream>>>(h2, dw_w, g);
    k_pout<<<BATCH*(LTOT/64)*2, 256, 0, stream>>>(g, pout_w, y2);
    k_fftker<<<(CDIM*64+255)/256, 256, 0, stream>>>(fft_p, kk);
    k_patchconv_res<<<(BATCH*CDIM*LTOT+255)/256, 256, 0, stream>>>(y2, kk, out);
}

// Round 6
// 364.481 us; speedup vs baseline: 7.3481x; 1.0893x over previous
//
#include <hip/hip_runtime.h>
#include <math.h>

#define BATCH   2
#define CDIM    64
#define DSTATE  8
#define DINNER  128
#define DTRANK  4
#define CDBL    20       // DTRANK + 2*DSTATE
#define HDIM    128
#define WDIM    128
#define LTOT    16384    // HDIM*WDIM
#define NHID    192      // HIDDEN

// ---- workspace offsets (floats) ----
static const size_t OFF_XF    = 0;            // 2*64*16384   = 2097152
static const size_t OFF_Z     = 2097152;      // (B,128,L)    = 4194304  (channel-major)
static const size_t OFF_XIN   = 6291456;      // (B,128,L)    = 4194304
static const size_t OFF_XS    = 10485760;     // (B,128,L)    = 4194304
static const size_t OFF_XDBL0 = 18874368;     // (B,20,L)     = 655360
static const size_t OFF_XDBL1 = 19529728;     // (B,20,L)     = 655360
static const size_t OFF_Y     = OFF_XIN;      // reuse xin
// EDFFN phase (reuses dead SS2D buffers)
static const size_t OFF_H2    = 0;            // (B,384,L)    = 12582912
static const size_t OFF_G     = 12582912;     // (B,192,L)    = 6291456
static const size_t OFF_Y2    = 18874368;     // (B,64,L)     = 2097152
static const size_t OFF_KK    = 21757952;     // 64*8*8       = 4096

__device__ __forceinline__ float gelu_exact(float x){
    return x * 0.5f * (1.0f + erff(x * 0.70710678118654752f));
}
__device__ __forceinline__ float softplus_f(float x){
    return (x > 20.0f) ? x : log1pf(expf(x));
}

// ---------------- K1: flip H,W ----------------
__global__ __launch_bounds__(256) void k_flip(const float* __restrict__ x, float* __restrict__ xf){
    int idx = blockIdx.x*256 + threadIdx.x;
    if (idx >= BATCH*CDIM*LTOT) return;
    int l = idx & (LTOT-1); int bc = idx >> 14;
    int h = l >> 7, w = l & (WDIM-1);
    xf[idx] = x[(size_t)bc*LTOT + (HDIM-1-h)*WDIM + (WDIM-1-w)];
}

// ------------- K2: wb_ln(norm1) + in_proj, LDS-tiled, output-split x4 -------------
__global__ __launch_bounds__(256) void k_ln_inproj(const float* __restrict__ xf,
        const float* __restrict__ nw, const float* __restrict__ nb,
        const float* __restrict__ Wp, float* __restrict__ xin, float* __restrict__ z){
    __shared__ float lx[CDIM][65];
    __shared__ float pr[4][64];
    __shared__ float rsA[64];
    int blk = blockIdx.x;
    int b = blk >> 10;
    int rem = blk & 1023;
    int l0 = (rem >> 2) << 6;
    int part = rem & 3;           // which 64-output slice
    int tid = threadIdx.x;
    for (int i=tid; i<CDIM*64; i+=256){
        int ch = i>>6, j = i&63;
        lx[ch][j] = xf[((size_t)b*CDIM+ch)*LTOT + l0 + j];
    }
    __syncthreads();
    {
        int pos = tid & 63, q = tid >> 6;
        float s = 0.f;
        for (int c=q*16; c<q*16+16; c++){ float v = lx[c][pos]; s += v*v; }
        pr[q][pos] = s;
    }
    __syncthreads();
    if (tid < 64){
        float t = pr[0][tid]+pr[1][tid]+pr[2][tid]+pr[3][tid];
        rsA[tid] = rsqrtf(t*(1.0f/CDIM) + 1e-6f);
    }
    __syncthreads();
    for (int i=tid; i<CDIM*64; i+=256){
        int ch = i>>6, j = i&63;
        lx[ch][j] = lx[ch][j]*rsA[j]*nw[ch] + nb[ch];
    }
    __syncthreads();
    int j = tid & 63;
    int grp = __builtin_amdgcn_readfirstlane(tid >> 6);   // wave-uniform -> scalar weight loads
    int o0 = part*64 + grp*16;
    float acc[16];
    #pragma unroll
    for (int oi=0;oi<16;oi++) acc[oi]=0.f;
    for (int cb=0; cb<8; cb++){
        float xv[8];
        #pragma unroll
        for (int cc=0;cc<8;cc++) xv[cc] = lx[cb*8+cc][j];
        #pragma unroll
        for (int oi=0;oi<16;oi++){
            const float* wr = Wp + (size_t)(o0+oi)*CDIM + cb*8;
            #pragma unroll
            for (int cc=0;cc<8;cc++) acc[oi] += xv[cc]*wr[cc];
        }
    }
    #pragma unroll
    for (int oi=0;oi<16;oi++){
        int o = o0+oi;
        float* dst = (o < DINNER) ? (xin + ((size_t)b*DINNER + o)*LTOT)
                                  : (z   + ((size_t)b*DINNER + (o-DINNER))*LTOT);
        dst[l0 + j] = acc[oi];
    }
}

// ------------- K3: depthwise conv2d 3x3 + gelu -------------
__global__ __launch_bounds__(256) void k_dwconv2d_gelu(const float* __restrict__ xin,
        const float* __restrict__ cw, const float* __restrict__ cb, float* __restrict__ xs){
    int idx = blockIdx.x*256 + threadIdx.x;
    if (idx >= BATCH*DINNER*LTOT) return;
    int l = idx & (LTOT-1); int bd = idx >> 14; int d = bd & (DINNER-1);
    int h = l >> 7, w = l & (WDIM-1);
    const float* base = xin + (size_t)bd*LTOT;
    float acc = cb[d];
    #pragma unroll
    for (int dh=-1; dh<=1; dh++){
        int hh = h+dh; if (hh<0||hh>=HDIM) continue;
        #pragma unroll
        for (int dw=-1; dw<=1; dw++){
            int ww = w+dw; if (ww<0||ww>=WDIM) continue;
            acc += base[hh*WDIM+ww] * cw[d*9 + (dh+1)*3 + (dw+1)];
        }
    }
    xs[idx] = gelu_exact(acc);
}

// ------------- K4: x_proj (128 -> 20) -------------
__global__ __launch_bounds__(256) void k_xproj(const float* __restrict__ xs,
        const float* __restrict__ Wx, float* __restrict__ xdbl_pre){
    int idx = blockIdx.x*256 + threadIdx.x;
    if (idx >= BATCH*LTOT) return;
    int b = idx >> 14, l = idx & (LTOT-1);
    float acc[CDBL];
    #pragma unroll
    for (int r=0;r<CDBL;r++) acc[r]=0.f;
    for (int d=0; d<DINNER; d++){
        float v = xs[((size_t)b*DINNER+d)*LTOT + l];
        #pragma unroll
        for (int r=0;r<CDBL;r++) acc[r] += v * Wx[r*DINNER+d];
    }
    #pragma unroll
    for (int r=0;r<CDBL;r++) xdbl_pre[((size_t)b*CDBL+r)*LTOT + l] = acc[r];
}

// ------------- K5: depthwise conv1d k=7 pad=3 + bias -------------
__global__ __launch_bounds__(256) void k_dwconv1d(const float* __restrict__ xp,
        const float* __restrict__ cw, const float* __restrict__ cb, float* __restrict__ xdbl){
    int idx = blockIdx.x*256 + threadIdx.x;
    if (idx >= BATCH*CDBL*LTOT) return;
    int l = idx & (LTOT-1); int br = idx >> 14; int r = br % CDBL;
    const float* base = xp + (size_t)br*LTOT;
    float acc = cb[r];
    #pragma unroll
    for (int k=0;k<7;k++){
        int t = l + k - 3;
        if (t>=0 && t<LTOT) acc += base[t]*cw[r*7+k];
    }
    xdbl[idx] = acc;
}

// ------------- K7: FUSED selective scan v2 — lane-serial-4 + (P,S) wave scan -------------
// One block per (b,d) row. 1024 threads = 16 waves; lane owns 4 consecutive
// timesteps (float4 loads). 4 outer iterations cover L=16384.
// Lane-local: AP[t][n]=prod of decays, SS[t][n]=partial state (zero init).
// Wave scan composes lane summaries (P,S); LDS composes the 16 waves;
// carry across iterations is a single scalar in wave0 lanes 0..7.
__global__ __launch_bounds__(1024) void k_scan_fused(const float* __restrict__ xdbl,
        const float* __restrict__ xs, const float* __restrict__ A_logs,
        const float* __restrict__ dtw, const float* __restrict__ dtb,
        const float* __restrict__ Ds, float* __restrict__ y){
    __shared__ float PSp[16][8];
    __shared__ float PSs[16][8];
    __shared__ float HIN[16][8];
    int bd = blockIdx.x;           // 0 .. 255
    int d  = bd & (DINNER-1);
    int b  = bd >> 7;
    int tid = threadIdx.x;
    int lane = tid & 63;
    int wv = tid >> 6;             // 0..15
    const float* xb = xdbl + (size_t)b*CDBL*LTOT;
    const float* xrow = xs + (size_t)bd*LTOT;
    float* yrow = y + (size_t)bd*LTOT;
    float A[DSTATE];
    #pragma unroll
    for (int n=0;n<DSTATE;n++) A[n] = -expf(A_logs[d*DSTATE+n]);
    float w0=dtw[d*DTRANK], w1=dtw[d*DTRANK+1], w2=dtw[d*DTRANK+2], w3=dtw[d*DTRANK+3];
    float dtbd = dtb[d];
    float Dd = Ds[d];
    float car = 0.f;               // carry: state n=lane, live in wave0 lanes 0..7

    for (int it=0; it<4; it++){
        int l0 = it*4096 + tid*4;
        // ---- coalesced float4 loads for dt inputs and x ----
        float4 r0 = *(const float4*)(xb + l0);
        float4 r1 = *(const float4*)(xb + LTOT + l0);
        float4 r2 = *(const float4*)(xb + 2*(size_t)LTOT + l0);
        float4 r3 = *(const float4*)(xb + 3*(size_t)LTOT + l0);
        float4 x4 = *(const float4*)(xrow + l0);
        float dt[4], dx[4];
        dt[0] = softplus_f(dtbd + r0.x*w0 + r1.x*w1 + r2.x*w2 + r3.x*w3);
        dt[1] = softplus_f(dtbd + r0.y*w0 + r1.y*w1 + r2.y*w2 + r3.y*w3);
        dt[2] = softplus_f(dtbd + r0.z*w0 + r1.z*w1 + r2.z*w2 + r3.z*w3);
        dt[3] = softplus_f(dtbd + r0.w*w0 + r1.w*w1 + r2.w*w2 + r3.w*w3);
        dx[0] = dt[0]*x4.x; dx[1] = dt[1]*x4.y; dx[2] = dt[2]*x4.z; dx[3] = dt[3]*x4.w;
        // ---- lane-local serial recurrence, per state ----
        float AP[4][DSTATE], SS[4][DSTATE];
        #pragma unroll
        for (int n=0;n<DSTATE;n++){
            float4 Bn = *(const float4*)(xb + (size_t)(DTRANK+n)*LTOT + l0);
            float ap = 1.f, s = 0.f;
            float a0 = __expf(A[n]*dt[0]); s = a0*s + dx[0]*Bn.x; ap *= a0; AP[0][n]=ap; SS[0][n]=s;
            float a1 = __expf(A[n]*dt[1]); s = a1*s + dx[1]*Bn.y; ap *= a1; AP[1][n]=ap; SS[1][n]=s;
            float a2 = __expf(A[n]*dt[2]); s = a2*s + dx[2]*Bn.z; ap *= a2; AP[2][n]=ap; SS[2][n]=s;
            float a3 = __expf(A[n]*dt[3]); s = a3*s + dx[3]*Bn.w; ap *= a3; AP[3][n]=ap; SS[3][n]=s;
        }
        // ---- wave scan on lane summaries (P,S) ----
        float scP[DSTATE], scS[DSTATE];
        #pragma unroll
        for (int n=0;n<DSTATE;n++){ scP[n]=AP[3][n]; scS[n]=SS[3][n]; }
        #pragma unroll
        for (int k=1;k<64;k<<=1){
            float Pu[DSTATE], Su[DSTATE];
            #pragma unroll
            for (int n=0;n<DSTATE;n++){ Pu[n]=__shfl_up(scP[n],k); Su[n]=__shfl_up(scS[n],k); }
            if (lane >= k){
                #pragma unroll
                for (int n=0;n<DSTATE;n++){ scS[n] = fmaf(scP[n], Su[n], scS[n]); scP[n] *= Pu[n]; }
            }
        }
        // ---- exclusive prefix (lane 0 -> identity) ----
        float exP[DSTATE], exS[DSTATE];
        #pragma unroll
        for (int n=0;n<DSTATE;n++){
            float p = __shfl_up(scP[n],1), s = __shfl_up(scS[n],1);
            exP[n] = (lane==0) ? 1.f : p;
            exS[n] = (lane==0) ? 0.f : s;
        }
        // ---- wave totals -> LDS ----
        if (lane == 63){
            #pragma unroll
            for (int n=0;n<DSTATE;n++){ PSp[wv][n]=scP[n]; PSs[wv][n]=scS[n]; }
        }
        __syncthreads();
        // ---- wave 0 composes the 16 waves (scalar carry) ----
        if (wv == 0 && lane < DSTATE){
            float h = car;
            #pragma unroll
            for (int w=0; w<16; w++){
                HIN[w][lane] = h;
                h = PSp[w][lane]*h + PSs[w][lane];
            }
            car = h;
        }
        __syncthreads();
        // ---- per-lane incoming state, finalize y ----
        float y0 = Dd*x4.x, y1 = Dd*x4.y, y2 = Dd*x4.z, y3 = Dd*x4.w;
        #pragma unroll
        for (int n=0;n<DSTATE;n++){
            float hin = fmaf(exP[n], HIN[wv][n], exS[n]);
            float4 Cn = *(const float4*)(xb + (size_t)(DTRANK+DSTATE+n)*LTOT + l0);
            y0 = fmaf(fmaf(AP[0][n], hin, SS[0][n]), Cn.x, y0);
            y1 = fmaf(fmaf(AP[1][n], hin, SS[1][n]), Cn.y, y1);
            y2 = fmaf(fmaf(AP[2][n], hin, SS[2][n]), Cn.z, y2);
            y3 = fmaf(fmaf(AP[3][n], hin, SS[3][n]), Cn.w, y3);
        }
        float4 yo; yo.x=y0; yo.y=y1; yo.z=y2; yo.w=y3;
        *(float4*)(yrow + l0) = yo;
    }
}

// ------------- K10: LN(y)*gelu(z) -> out_proj -> + xf, output-split x2 -------------
__global__ __launch_bounds__(256) void k_gate_out(const float* __restrict__ y,
        const float* __restrict__ z, const float* __restrict__ onw, const float* __restrict__ onb,
        const float* __restrict__ Wout, const float* __restrict__ xf, float* __restrict__ out){
    __shared__ float ly[DINNER][65];
    __shared__ float pr1[4][64], pr2[4][64];
    __shared__ float muA[64], rsA[64];
    int blk = blockIdx.x;
    int b = blk >> 9;
    int rem = blk & 511;
    int l0 = (rem >> 1) << 6;
    int part = rem & 1;
    int tid = threadIdx.x;
    for (int i=tid; i<DINNER*64; i+=256){
        int dd = i>>6, j = i&63;
        ly[dd][j] = y[((size_t)b*DINNER+dd)*LTOT + l0 + j];
    }
    __syncthreads();
    {
        int pos = tid & 63, q = tid >> 6;
        float s1=0.f, s2=0.f;
        for (int dd=q*32; dd<q*32+32; dd++){ float v = ly[dd][pos]; s1+=v; s2+=v*v; }
        pr1[q][pos]=s1; pr2[q][pos]=s2;
    }
    __syncthreads();
    if (tid < 64){
        float s1 = pr1[0][tid]+pr1[1][tid]+pr1[2][tid]+pr1[3][tid];
        float s2 = pr2[0][tid]+pr2[1][tid]+pr2[2][tid]+pr2[3][tid];
        float mu = s1*(1.0f/DINNER);
        float var = s2*(1.0f/DINNER) - mu*mu;
        muA[tid]=mu; rsA[tid]=rsqrtf(var + 1e-5f);
    }
    __syncthreads();
    for (int i=tid; i<DINNER*64; i+=256){
        int dd = i>>6, j = i&63;
        float zv = z[((size_t)b*DINNER+dd)*LTOT + l0 + j];
        ly[dd][j] = ((ly[dd][j]-muA[j])*rsA[j]*onw[dd] + onb[dd]) * gelu_exact(zv);
    }
    __syncthreads();
    int j = tid & 63;
    int grp = __builtin_amdgcn_readfirstlane(tid >> 6);
    int o0 = part*32 + grp*8;
    float acc[8];
    #pragma unroll
    for (int oi=0;oi<8;oi++) acc[oi]=0.f;
    for (int cb=0; cb<16; cb++){
        float xv[8];
        #pragma unroll
        for (int cc=0;cc<8;cc++) xv[cc] = ly[cb*8+cc][j];
        #pragma unroll
        for (int oi=0;oi<8;oi++){
            const float* wr = Wout + (size_t)(o0+oi)*DINNER + cb*8;
            #pragma unroll
            for (int cc=0;cc<8;cc++) acc[oi] += xv[cc]*wr[cc];
        }
    }
    #pragma unroll
    for (int oi=0;oi<8;oi++){
        size_t off = ((size_t)b*CDIM + o0+oi)*LTOT + l0 + j;
        out[off] = xf[off] + acc[oi];
    }
}

// ------------- K11: wb_ln(norm2) + pin (64 -> 384), output-split x4 -------------
__global__ __launch_bounds__(256) void k_ln_pin(const float* __restrict__ x2,
        const float* __restrict__ nw, const float* __restrict__ nb,
        const float* __restrict__ Wp, float* __restrict__ h2){
    __shared__ float lx[CDIM][65];
    __shared__ float pr[4][64];
    __shared__ float rsA[64];
    int blk = blockIdx.x;
    int b = blk >> 10;
    int rem = blk & 1023;
    int l0 = (rem >> 2) << 6;
    int part = rem & 3;
    int tid = threadIdx.x;
    for (int i=tid; i<CDIM*64; i+=256){
        int ch = i>>6, j = i&63;
        lx[ch][j] = x2[((size_t)b*CDIM+ch)*LTOT + l0 + j];
    }
    __syncthreads();
    {
        int pos = tid & 63, q = tid >> 6;
        float s = 0.f;
        for (int c=q*16; c<q*16+16; c++){ float v = lx[c][pos]; s += v*v; }
        pr[q][pos] = s;
    }
    __syncthreads();
    if (tid < 64){
        float t = pr[0][tid]+pr[1][tid]+pr[2][tid]+pr[3][tid];
        rsA[tid] = rsqrtf(t*(1.0f/CDIM) + 1e-6f);
    }
    __syncthreads();
    for (int i=tid; i<CDIM*64; i+=256){
        int ch = i>>6, j = i&63;
        lx[ch][j] = lx[ch][j]*rsA[j]*nw[ch] + nb[ch];
    }
    __syncthreads();
    int j = tid & 63;
    int grp = __builtin_amdgcn_readfirstlane(tid >> 6);
    int o0 = part*96 + grp*24;
    float acc[24];
    #pragma unroll
    for (int oi=0;oi<24;oi++) acc[oi]=0.f;
    for (int cb=0; cb<8; cb++){
        float xv[8];
        #pragma unroll
        for (int cc=0;cc<8;cc++) xv[cc] = lx[cb*8+cc][j];
        #pragma unroll
        for (int oi=0;oi<24;oi++){
            const float* wr = Wp + (size_t)(o0+oi)*CDIM + cb*8;
            #pragma unroll
            for (int cc=0;cc<8;cc++) acc[oi] += xv[cc]*wr[cc];
        }
    }
    #pragma unroll
    for (int oi=0;oi<24;oi++){
        h2[((size_t)b*2*NHID + o0+oi)*LTOT + l0 + j] = acc[oi];
    }
}

// ------------- K12: dwconv2d 3x3 (no bias) + gelu-gate -------------
__global__ __launch_bounds__(256) void k_dwconv_gate(const float* __restrict__ h2,
        const float* __restrict__ dww, float* __restrict__ g){
    int idx = blockIdx.x*256 + threadIdx.x;
    if (idx >= BATCH*NHID*LTOT) return;
    int l = idx & (LTOT-1); int bc = idx >> 14; int ch = bc % NHID; int b = bc / NHID;
    int h = l >> 7, w = l & (WDIM-1);
    const float* b1 = h2 + ((size_t)b*2*NHID + ch)*LTOT;
    const float* b2 = b1 + (size_t)NHID*LTOT;
    float a1=0.f, a2=0.f;
    #pragma unroll
    for (int dh=-1; dh<=1; dh++){
        int hh = h+dh; if (hh<0||hh>=HDIM) continue;
        #pragma unroll
        for (int dw=-1; dw<=1; dw++){
            int ww = w+dw; if (ww<0||ww>=WDIM) continue;
            int tap = (dh+1)*3 + (dw+1);
            a1 += b1[hh*WDIM+ww] * dww[ch*9 + tap];
            a2 += b2[hh*WDIM+ww] * dww[(ch+NHID)*9 + tap];
        }
    }
    g[idx] = gelu_exact(a1)*a2;
}

// ------------- K13: pout (192 -> 64), output-split x2 -------------
__global__ __launch_bounds__(256) void k_pout(const float* __restrict__ g,
        const float* __restrict__ Wp, float* __restrict__ y2){
    __shared__ float lg[NHID][65];
    int blk = blockIdx.x;
    int b = blk >> 9;
    int rem = blk & 511;
    int l0 = (rem >> 1) << 6;
    int part = rem & 1;
    int tid = threadIdx.x;
    for (int i=tid; i<NHID*64; i+=256){
        int c = i>>6, j = i&63;
        lg[c][j] = g[((size_t)b*NHID+c)*LTOT + l0 + j];
    }
    __syncthreads();
    int j = tid & 63;
    int grp = __builtin_amdgcn_readfirstlane(tid >> 6);
    int o0 = part*32 + grp*8;
    float acc[8];
    #pragma unroll
    for (int oi=0;oi<8;oi++) acc[oi]=0.f;
    for (int cb=0; cb<24; cb++){
        float xv[8];
        #pragma unroll
        for (int cc=0;cc<8;cc++) xv[cc] = lg[cb*8+cc][j];
        #pragma unroll
        for (int oi=0;oi<8;oi++){
            const float* wr = Wp + (size_t)(o0+oi)*NHID + cb*8;
            #pragma unroll
            for (int cc=0;cc<8;cc++) acc[oi] += xv[cc]*wr[cc];
        }
    }
    #pragma unroll
    for (int oi=0;oi<8;oi++){
        y2[((size_t)b*CDIM + o0+oi)*LTOT + l0 + j] = acc[oi];
    }
}

// ------------- K14a: build per-channel 8x8 circular kernel from fft_p -------------
__global__ __launch_bounds__(256) void k_fftker(const float* __restrict__ fp, float* __restrict__ kk){
    int idx = blockIdx.x*256 + threadIdx.x;
    if (idx >= CDIM*64) return;
    int c = idx >> 6, tap = idx & 63;
    int dm = tap >> 3, dn = tap & 7;
    const float R = 0.70710678118654752f;
    const float ct[8] = {1.f, R, 0.f, -R, -1.f, -R, 0.f, R};
    const float* fc = fp + c*40;
    float s = 0.f;
    #pragma unroll
    for (int u=0; u<8; u++){
        #pragma unroll
        for (int v=0; v<8; v++){
            float m1 = (v<=4) ? fc[u*5 + v]
                              : fc[((8-u)&7)*5 + (8-v)];
            int u2 = (8-u)&7, v2 = (8-v)&7;
            float m2 = (v2<=4) ? fc[u2*5 + v2]
                               : fc[((8-u2)&7)*5 + (8-v2)];
            float Ms = 0.5f*(m1+m2);
            s += Ms * ct[(u*dm + v*dn)&7];
        }
    }
    kk[c*64 + dm*8 + dn] = s * (1.0f/64.0f);
}

// ------------- K14b: per-patch circular conv + residual (in-place on d_out) -------------
__global__ __launch_bounds__(256) void k_patchconv_res(const float* __restrict__ y2,
        const float* __restrict__ kk, float* __restrict__ out){
    int idx = blockIdx.x*256 + threadIdx.x;
    if (idx >= BATCH*CDIM*LTOT) return;
    int l = idx & (LTOT-1); int bc = idx >> 14; int c = bc & (CDIM-1);
    int h = l >> 7, w = l & (WDIM-1);
    int hb = h>>3, hi = h&7, wb = w>>3, wi = w&7;
    const float* yb = y2 + (size_t)bc*LTOT + (hb*8)*WDIM + wb*8;
    const float* kc = kk + c*64;
    float acc = 0.f;
    #pragma unroll
    for (int m=0;m<8;m++){
        #pragma unroll
        for (int n=0;n<8;n++){
            acc += yb[m*WDIM + n] * kc[((hi-m)&7)*8 + ((wi-n)&7)];
        }
    }
    out[idx] += acc;
}

extern "C" void kernel_launch(void* const* d_in, const int* in_sizes, int n_in,
                              void* d_out, int out_size, void* d_ws, size_t ws_size,
                              hipStream_t stream){
    const float* x         = (const float*)d_in[0];
    const float* norm1_w   = (const float*)d_in[1];
    const float* norm1_b   = (const float*)d_in[2];
    const float* in_proj_w = (const float*)d_in[3];
    const float* conv2d_w  = (const float*)d_in[4];
    const float* conv2d_b  = (const float*)d_in[5];
    const float* x_proj_w  = (const float*)d_in[6];
    const float* x_conv_w  = (const float*)d_in[7];
    const float* x_conv_b  = (const float*)d_in[8];
    const float* dt_projs_w= (const float*)d_in[9];
    const float* dt_projs_b= (const float*)d_in[10];
    const float* A_logs    = (const float*)d_in[11];
    const float* Ds        = (const float*)d_in[12];
    const float* out_norm_w= (const float*)d_in[13];
    const float* out_norm_b= (const float*)d_in[14];
    const float* out_proj_w= (const float*)d_in[15];
    const float* norm2_w   = (const float*)d_in[16];
    const float* norm2_b   = (const float*)d_in[17];
    const float* pin_w     = (const float*)d_in[18];
    const float* dw_w      = (const float*)d_in[19];
    const float* fft_p     = (const float*)d_in[20];
    const float* pout_w    = (const float*)d_in[21];
    float* out = (float*)d_out;
    float* ws  = (float*)d_ws;

    float* xf    = ws + OFF_XF;
    float* z     = ws + OFF_Z;
    float* xin   = ws + OFF_XIN;
    float* xs    = ws + OFF_XS;
    float* xdbl0 = ws + OFF_XDBL0;
    float* xdbl1 = ws + OFF_XDBL1;
    float* y     = ws + OFF_Y;
    float* h2    = ws + OFF_H2;
    float* g     = ws + OFF_G;
    float* y2    = ws + OFF_Y2;
    float* kk    = ws + OFF_KK;

    // ---- SS2D branch ----
    k_flip<<<(BATCH*CDIM*LTOT+255)/256, 256, 0, stream>>>(x, xf);
    k_ln_inproj<<<BATCH*(LTOT/64)*4, 256, 0, stream>>>(xf, norm1_w, norm1_b, in_proj_w, xin, z);
    k_dwconv2d_gelu<<<(BATCH*DINNER*LTOT+255)/256, 256, 0, stream>>>(xin, conv2d_w, conv2d_b, xs);
    k_xproj<<<(BATCH*LTOT+255)/256, 256, 0, stream>>>(xs, x_proj_w, xdbl0);
    k_dwconv1d<<<(BATCH*CDBL*LTOT+255)/256, 256, 0, stream>>>(xdbl0, x_conv_w, x_conv_b, xdbl1);
    k_scan_fused<<<BATCH*DINNER, 1024, 0, stream>>>(xdbl1, xs, A_logs, dt_projs_w, dt_projs_b, Ds, y);
    k_gate_out<<<BATCH*(LTOT/64)*2, 256, 0, stream>>>(y, z, out_norm_w, out_norm_b, out_proj_w, xf, out);

    // ---- EDFFN branch (out currently holds x2) ----
    k_ln_pin<<<BATCH*(LTOT/64)*4, 256, 0, stream>>>(out, norm2_w, norm2_b, pin_w, h2);
    k_dwconv_gate<<<(BATCH*NHID*LTOT+255)/256, 256, 0, stream>>>(h2, dw_w, g);
    k_pout<<<BATCH*(LTOT/64)*2, 256, 0, stream>>>(g, pout_w, y2);
    k_fftker<<<(CDIM*64+255)/256, 256, 0, stream>>>(fft_p, kk);
    k_patchconv_res<<<(BATCH*CDIM*LTOT+255)/256, 256, 0, stream>>>(y2, kk, out);
}

// Round 7
// 313.969 us; speedup vs baseline: 8.5303x; 1.1609x over previous
//
#include <hip/hip_runtime.h>
#include <math.h>

#define BATCH   2
#define CDIM    64
#define DSTATE  8
#define DINNER  128
#define DTRANK  4
#define CDBL    20       // DTRANK + 2*DSTATE
#define HDIM    128
#define WDIM    128
#define LTOT    16384    // HDIM*WDIM
#define NHID    192      // HIDDEN

// ---- workspace offsets (floats) ----
static const size_t OFF_XF    = 0;            // 2*64*16384   = 2097152
static const size_t OFF_Z     = 2097152;      // (B,128,L)    = 4194304  (channel-major)
static const size_t OFF_XIN   = 6291456;      // (B,128,L)    = 4194304
static const size_t OFF_XS    = 10485760;     // (B,128,L)    = 4194304
static const size_t OFF_XDBL0 = 18874368;     // (B,20,L)     = 655360
static const size_t OFF_XDBL1 = 19529728;     // (B,20,L)     = 655360
static const size_t OFF_Y     = OFF_XIN;      // reuse xin
// EDFFN phase (reuses dead SS2D buffers)
static const size_t OFF_H2    = 0;            // (B,384,L)    = 12582912
static const size_t OFF_G     = 12582912;     // (B,192,L)    = 6291456
static const size_t OFF_Y2    = 18874368;     // (B,64,L)     = 2097152
static const size_t OFF_KK    = 21757952;     // 64*8*8       = 4096

__device__ __forceinline__ float gelu_exact(float x){
    return x * 0.5f * (1.0f + erff(x * 0.70710678118654752f));
}
__device__ __forceinline__ float softplus_f(float x){
    return (x > 20.0f) ? x : log1pf(expf(x));
}

// ---------------- K1: flip H,W ----------------
__global__ __launch_bounds__(256) void k_flip(const float* __restrict__ x, float* __restrict__ xf){
    int idx = blockIdx.x*256 + threadIdx.x;
    if (idx >= BATCH*CDIM*LTOT) return;
    int l = idx & (LTOT-1); int bc = idx >> 14;
    int h = l >> 7, w = l & (WDIM-1);
    xf[idx] = x[(size_t)bc*LTOT + (HDIM-1-h)*WDIM + (WDIM-1-w)];
}

// ------------- K2: wb_ln(norm1) + in_proj, LDS-tiled, output-split x4 -------------
__global__ __launch_bounds__(256) void k_ln_inproj(const float* __restrict__ xf,
        const float* __restrict__ nw, const float* __restrict__ nb,
        const float* __restrict__ Wp, float* __restrict__ xin, float* __restrict__ z){
    __shared__ float lx[CDIM][65];
    __shared__ float pr[4][64];
    __shared__ float rsA[64];
    int blk = blockIdx.x;
    int b = blk >> 10;
    int rem = blk & 1023;
    int l0 = (rem >> 2) << 6;
    int part = rem & 3;           // which 64-output slice
    int tid = threadIdx.x;
    for (int i=tid; i<CDIM*64; i+=256){
        int ch = i>>6, j = i&63;
        lx[ch][j] = xf[((size_t)b*CDIM+ch)*LTOT + l0 + j];
    }
    __syncthreads();
    {
        int pos = tid & 63, q = tid >> 6;
        float s = 0.f;
        for (int c=q*16; c<q*16+16; c++){ float v = lx[c][pos]; s += v*v; }
        pr[q][pos] = s;
    }
    __syncthreads();
    if (tid < 64){
        float t = pr[0][tid]+pr[1][tid]+pr[2][tid]+pr[3][tid];
        rsA[tid] = rsqrtf(t*(1.0f/CDIM) + 1e-6f);
    }
    __syncthreads();
    for (int i=tid; i<CDIM*64; i+=256){
        int ch = i>>6, j = i&63;
        lx[ch][j] = lx[ch][j]*rsA[j]*nw[ch] + nb[ch];
    }
    __syncthreads();
    int j = tid & 63;
    int grp = __builtin_amdgcn_readfirstlane(tid >> 6);   // wave-uniform -> scalar weight loads
    int o0 = part*64 + grp*16;
    float acc[16];
    #pragma unroll
    for (int oi=0;oi<16;oi++) acc[oi]=0.f;
    for (int cb=0; cb<8; cb++){
        float xv[8];
        #pragma unroll
        for (int cc=0;cc<8;cc++) xv[cc] = lx[cb*8+cc][j];
        #pragma unroll
        for (int oi=0;oi<16;oi++){
            const float* wr = Wp + (size_t)(o0+oi)*CDIM + cb*8;
            #pragma unroll
            for (int cc=0;cc<8;cc++) acc[oi] += xv[cc]*wr[cc];
        }
    }
    #pragma unroll
    for (int oi=0;oi<16;oi++){
        int o = o0+oi;
        float* dst = (o < DINNER) ? (xin + ((size_t)b*DINNER + o)*LTOT)
                                  : (z   + ((size_t)b*DINNER + (o-DINNER))*LTOT);
        dst[l0 + j] = acc[oi];
    }
}

// ------------- K3: depthwise conv2d 3x3 + gelu -------------
__global__ __launch_bounds__(256) void k_dwconv2d_gelu(const float* __restrict__ xin,
        const float* __restrict__ cw, const float* __restrict__ cb, float* __restrict__ xs){
    int idx = blockIdx.x*256 + threadIdx.x;
    if (idx >= BATCH*DINNER*LTOT) return;
    int l = idx & (LTOT-1); int bd = idx >> 14; int d = bd & (DINNER-1);
    int h = l >> 7, w = l & (WDIM-1);
    const float* base = xin + (size_t)bd*LTOT;
    float acc = cb[d];
    #pragma unroll
    for (int dh=-1; dh<=1; dh++){
        int hh = h+dh; if (hh<0||hh>=HDIM) continue;
        #pragma unroll
        for (int dw=-1; dw<=1; dw++){
            int ww = w+dw; if (ww<0||ww>=WDIM) continue;
            acc += base[hh*WDIM+ww] * cw[d*9 + (dh+1)*3 + (dw+1)];
        }
    }
    xs[idx] = gelu_exact(acc);
}

// ------------- K4: x_proj (128 -> 20) -------------
__global__ __launch_bounds__(256) void k_xproj(const float* __restrict__ xs,
        const float* __restrict__ Wx, float* __restrict__ xdbl_pre){
    int idx = blockIdx.x*256 + threadIdx.x;
    if (idx >= BATCH*LTOT) return;
    int b = idx >> 14, l = idx & (LTOT-1);
    float acc[CDBL];
    #pragma unroll
    for (int r=0;r<CDBL;r++) acc[r]=0.f;
    for (int d=0; d<DINNER; d++){
        float v = xs[((size_t)b*DINNER+d)*LTOT + l];
        #pragma unroll
        for (int r=0;r<CDBL;r++) acc[r] += v * Wx[r*DINNER+d];
    }
    #pragma unroll
    for (int r=0;r<CDBL;r++) xdbl_pre[((size_t)b*CDBL+r)*LTOT + l] = acc[r];
}

// ------------- K5: depthwise conv1d k=7 pad=3 + bias -------------
__global__ __launch_bounds__(256) void k_dwconv1d(const float* __restrict__ xp,
        const float* __restrict__ cw, const float* __restrict__ cb, float* __restrict__ xdbl){
    int idx = blockIdx.x*256 + threadIdx.x;
    if (idx >= BATCH*CDBL*LTOT) return;
    int l = idx & (LTOT-1); int br = idx >> 14; int r = br % CDBL;
    const float* base = xp + (size_t)br*LTOT;
    float acc = cb[r];
    #pragma unroll
    for (int k=0;k<7;k++){
        int t = l + k - 3;
        if (t>=0 && t<LTOT) acc += base[t]*cw[r*7+k];
    }
    xdbl[idx] = acc;
}

// ------------- K7: FUSED selective scan v2 — lane-serial-4 + (P,S) wave scan -------------
__global__ __launch_bounds__(1024) void k_scan_fused(const float* __restrict__ xdbl,
        const float* __restrict__ xs, const float* __restrict__ A_logs,
        const float* __restrict__ dtw, const float* __restrict__ dtb,
        const float* __restrict__ Ds, float* __restrict__ y){
    __shared__ float PSp[16][8];
    __shared__ float PSs[16][8];
    __shared__ float HIN[16][8];
    int bd = blockIdx.x;           // 0 .. 255
    int d  = bd & (DINNER-1);
    int b  = bd >> 7;
    int tid = threadIdx.x;
    int lane = tid & 63;
    int wv = tid >> 6;             // 0..15
    const float* xb = xdbl + (size_t)b*CDBL*LTOT;
    const float* xrow = xs + (size_t)bd*LTOT;
    float* yrow = y + (size_t)bd*LTOT;
    float A[DSTATE];
    #pragma unroll
    for (int n=0;n<DSTATE;n++) A[n] = -expf(A_logs[d*DSTATE+n]);
    float w0=dtw[d*DTRANK], w1=dtw[d*DTRANK+1], w2=dtw[d*DTRANK+2], w3=dtw[d*DTRANK+3];
    float dtbd = dtb[d];
    float Dd = Ds[d];
    float car = 0.f;               // carry: state n=lane, live in wave0 lanes 0..7

    for (int it=0; it<4; it++){
        int l0 = it*4096 + tid*4;
        float4 r0 = *(const float4*)(xb + l0);
        float4 r1 = *(const float4*)(xb + LTOT + l0);
        float4 r2 = *(const float4*)(xb + 2*(size_t)LTOT + l0);
        float4 r3 = *(const float4*)(xb + 3*(size_t)LTOT + l0);
        float4 x4 = *(const float4*)(xrow + l0);
        float dt[4], dx[4];
        dt[0] = softplus_f(dtbd + r0.x*w0 + r1.x*w1 + r2.x*w2 + r3.x*w3);
        dt[1] = softplus_f(dtbd + r0.y*w0 + r1.y*w1 + r2.y*w2 + r3.y*w3);
        dt[2] = softplus_f(dtbd + r0.z*w0 + r1.z*w1 + r2.z*w2 + r3.z*w3);
        dt[3] = softplus_f(dtbd + r0.w*w0 + r1.w*w1 + r2.w*w2 + r3.w*w3);
        dx[0] = dt[0]*x4.x; dx[1] = dt[1]*x4.y; dx[2] = dt[2]*x4.z; dx[3] = dt[3]*x4.w;
        float AP[4][DSTATE], SS[4][DSTATE];
        #pragma unroll
        for (int n=0;n<DSTATE;n++){
            float4 Bn = *(const float4*)(xb + (size_t)(DTRANK+n)*LTOT + l0);
            float ap = 1.f, s = 0.f;
            float a0 = __expf(A[n]*dt[0]); s = a0*s + dx[0]*Bn.x; ap *= a0; AP[0][n]=ap; SS[0][n]=s;
            float a1 = __expf(A[n]*dt[1]); s = a1*s + dx[1]*Bn.y; ap *= a1; AP[1][n]=ap; SS[1][n]=s;
            float a2 = __expf(A[n]*dt[2]); s = a2*s + dx[2]*Bn.z; ap *= a2; AP[2][n]=ap; SS[2][n]=s;
            float a3 = __expf(A[n]*dt[3]); s = a3*s + dx[3]*Bn.w; ap *= a3; AP[3][n]=ap; SS[3][n]=s;
        }
        float scP[DSTATE], scS[DSTATE];
        #pragma unroll
        for (int n=0;n<DSTATE;n++){ scP[n]=AP[3][n]; scS[n]=SS[3][n]; }
        #pragma unroll
        for (int k=1;k<64;k<<=1){
            float Pu[DSTATE], Su[DSTATE];
            #pragma unroll
            for (int n=0;n<DSTATE;n++){ Pu[n]=__shfl_up(scP[n],k); Su[n]=__shfl_up(scS[n],k); }
            if (lane >= k){
                #pragma unroll
                for (int n=0;n<DSTATE;n++){ scS[n] = fmaf(scP[n], Su[n], scS[n]); scP[n] *= Pu[n]; }
            }
        }
        float exP[DSTATE], exS[DSTATE];
        #pragma unroll
        for (int n=0;n<DSTATE;n++){
            float p = __shfl_up(scP[n],1), s = __shfl_up(scS[n],1);
            exP[n] = (lane==0) ? 1.f : p;
            exS[n] = (lane==0) ? 0.f : s;
        }
        if (lane == 63){
            #pragma unroll
            for (int n=0;n<DSTATE;n++){ PSp[wv][n]=scP[n]; PSs[wv][n]=scS[n]; }
        }
        __syncthreads();
        if (wv == 0 && lane < DSTATE){
            float h = car;
            #pragma unroll
            for (int w=0; w<16; w++){
                HIN[w][lane] = h;
                h = PSp[w][lane]*h + PSs[w][lane];
            }
            car = h;
        }
        __syncthreads();
        float y0 = Dd*x4.x, y1 = Dd*x4.y, y2 = Dd*x4.z, y3 = Dd*x4.w;
        #pragma unroll
        for (int n=0;n<DSTATE;n++){
            float hin = fmaf(exP[n], HIN[wv][n], exS[n]);
            float4 Cn = *(const float4*)(xb + (size_t)(DTRANK+DSTATE+n)*LTOT + l0);
            y0 = fmaf(fmaf(AP[0][n], hin, SS[0][n]), Cn.x, y0);
            y1 = fmaf(fmaf(AP[1][n], hin, SS[1][n]), Cn.y, y1);
            y2 = fmaf(fmaf(AP[2][n], hin, SS[2][n]), Cn.z, y2);
            y3 = fmaf(fmaf(AP[3][n], hin, SS[3][n]), Cn.w, y3);
        }
        float4 yo; yo.x=y0; yo.y=y1; yo.z=y2; yo.w=y3;
        *(float4*)(yrow + l0) = yo;
    }
}

// ------------- K10: LN(y)*gelu(z) -> out_proj -> + xf, output-split x2 -------------
__global__ __launch_bounds__(256) void k_gate_out(const float* __restrict__ y,
        const float* __restrict__ z, const float* __restrict__ onw, const float* __restrict__ onb,
        const float* __restrict__ Wout, const float* __restrict__ xf, float* __restrict__ out){
    __shared__ float ly[DINNER][65];
    __shared__ float pr1[4][64], pr2[4][64];
    __shared__ float muA[64], rsA[64];
    int blk = blockIdx.x;
    int b = blk >> 9;
    int rem = blk & 511;
    int l0 = (rem >> 1) << 6;
    int part = rem & 1;
    int tid = threadIdx.x;
    for (int i=tid; i<DINNER*64; i+=256){
        int dd = i>>6, j = i&63;
        ly[dd][j] = y[((size_t)b*DINNER+dd)*LTOT + l0 + j];
    }
    __syncthreads();
    {
        int pos = tid & 63, q = tid >> 6;
        float s1=0.f, s2=0.f;
        for (int dd=q*32; dd<q*32+32; dd++){ float v = ly[dd][pos]; s1+=v; s2+=v*v; }
        pr1[q][pos]=s1; pr2[q][pos]=s2;
    }
    __syncthreads();
    if (tid < 64){
        float s1 = pr1[0][tid]+pr1[1][tid]+pr1[2][tid]+pr1[3][tid];
        float s2 = pr2[0][tid]+pr2[1][tid]+pr2[2][tid]+pr2[3][tid];
        float mu = s1*(1.0f/DINNER);
        float var = s2*(1.0f/DINNER) - mu*mu;
        muA[tid]=mu; rsA[tid]=rsqrtf(var + 1e-5f);
    }
    __syncthreads();
    for (int i=tid; i<DINNER*64; i+=256){
        int dd = i>>6, j = i&63;
        float zv = z[((size_t)b*DINNER+dd)*LTOT + l0 + j];
        ly[dd][j] = ((ly[dd][j]-muA[j])*rsA[j]*onw[dd] + onb[dd]) * gelu_exact(zv);
    }
    __syncthreads();
    int j = tid & 63;
    int grp = __builtin_amdgcn_readfirstlane(tid >> 6);
    int o0 = part*32 + grp*8;
    float acc[8];
    #pragma unroll
    for (int oi=0;oi<8;oi++) acc[oi]=0.f;
    for (int cb=0; cb<16; cb++){
        float xv[8];
        #pragma unroll
        for (int cc=0;cc<8;cc++) xv[cc] = ly[cb*8+cc][j];
        #pragma unroll
        for (int oi=0;oi<8;oi++){
            const float* wr = Wout + (size_t)(o0+oi)*DINNER + cb*8;
            #pragma unroll
            for (int cc=0;cc<8;cc++) acc[oi] += xv[cc]*wr[cc];
        }
    }
    #pragma unroll
    for (int oi=0;oi<8;oi++){
        size_t off = ((size_t)b*CDIM + o0+oi)*LTOT + l0 + j;
        out[off] = xf[off] + acc[oi];
    }
}

// ------------- K11: wb_ln(norm2) + pin (64 -> 384), output-split x4 -------------
__global__ __launch_bounds__(256) void k_ln_pin(const float* __restrict__ x2,
        const float* __restrict__ nw, const float* __restrict__ nb,
        const float* __restrict__ Wp, float* __restrict__ h2){
    __shared__ float lx[CDIM][65];
    __shared__ float pr[4][64];
    __shared__ float rsA[64];
    int blk = blockIdx.x;
    int b = blk >> 10;
    int rem = blk & 1023;
    int l0 = (rem >> 2) << 6;
    int part = rem & 3;
    int tid = threadIdx.x;
    for (int i=tid; i<CDIM*64; i+=256){
        int ch = i>>6, j = i&63;
        lx[ch][j] = x2[((size_t)b*CDIM+ch)*LTOT + l0 + j];
    }
    __syncthreads();
    {
        int pos = tid & 63, q = tid >> 6;
        float s = 0.f;
        for (int c=q*16; c<q*16+16; c++){ float v = lx[c][pos]; s += v*v; }
        pr[q][pos] = s;
    }
    __syncthreads();
    if (tid < 64){
        float t = pr[0][tid]+pr[1][tid]+pr[2][tid]+pr[3][tid];
        rsA[tid] = rsqrtf(t*(1.0f/CDIM) + 1e-6f);
    }
    __syncthreads();
    for (int i=tid; i<CDIM*64; i+=256){
        int ch = i>>6, j = i&63;
        lx[ch][j] = lx[ch][j]*rsA[j]*nw[ch] + nb[ch];
    }
    __syncthreads();
    int j = tid & 63;
    int grp = __builtin_amdgcn_readfirstlane(tid >> 6);
    int o0 = part*96 + grp*24;
    float acc[24];
    #pragma unroll
    for (int oi=0;oi<24;oi++) acc[oi]=0.f;
    for (int cb=0; cb<8; cb++){
        float xv[8];
        #pragma unroll
        for (int cc=0;cc<8;cc++) xv[cc] = lx[cb*8+cc][j];
        #pragma unroll
        for (int oi=0;oi<24;oi++){
            const float* wr = Wp + (size_t)(o0+oi)*CDIM + cb*8;
            #pragma unroll
            for (int cc=0;cc<8;cc++) acc[oi] += xv[cc]*wr[cc];
        }
    }
    #pragma unroll
    for (int oi=0;oi<24;oi++){
        h2[((size_t)b*2*NHID + o0+oi)*LTOT + l0 + j] = acc[oi];
    }
}

// ------------- K12: dwconv2d 3x3 (no bias) + gelu-gate -------------
__global__ __launch_bounds__(256) void k_dwconv_gate(const float* __restrict__ h2,
        const float* __restrict__ dww, float* __restrict__ g){
    int idx = blockIdx.x*256 + threadIdx.x;
    if (idx >= BATCH*NHID*LTOT) return;
    int l = idx & (LTOT-1); int bc = idx >> 14; int ch = bc % NHID; int b = bc / NHID;
    int h = l >> 7, w = l & (WDIM-1);
    const float* b1 = h2 + ((size_t)b*2*NHID + ch)*LTOT;
    const float* b2 = b1 + (size_t)NHID*LTOT;
    float a1=0.f, a2=0.f;
    #pragma unroll
    for (int dh=-1; dh<=1; dh++){
        int hh = h+dh; if (hh<0||hh>=HDIM) continue;
        #pragma unroll
        for (int dw=-1; dw<=1; dw++){
            int ww = w+dw; if (ww<0||ww>=WDIM) continue;
            int tap = (dh+1)*3 + (dw+1);
            a1 += b1[hh*WDIM+ww] * dww[ch*9 + tap];
            a2 += b2[hh*WDIM+ww] * dww[(ch+NHID)*9 + tap];
        }
    }
    g[idx] = gelu_exact(a1)*a2;
}

// ------------- K13: pout (192 -> 64), output-split x2 -------------
__global__ __launch_bounds__(256) void k_pout(const float* __restrict__ g,
        const float* __restrict__ Wp, float* __restrict__ y2){
    __shared__ float lg[NHID][65];
    int blk = blockIdx.x;
    int b = blk >> 9;
    int rem = blk & 511;
    int l0 = (rem >> 1) << 6;
    int part = rem & 1;
    int tid = threadIdx.x;
    for (int i=tid; i<NHID*64; i+=256){
        int c = i>>6, j = i&63;
        lg[c][j] = g[((size_t)b*NHID+c)*LTOT + l0 + j];
    }
    __syncthreads();
    int j = tid & 63;
    int grp = __builtin_amdgcn_readfirstlane(tid >> 6);
    int o0 = part*32 + grp*8;
    float acc[8];
    #pragma unroll
    for (int oi=0;oi<8;oi++) acc[oi]=0.f;
    for (int cb=0; cb<24; cb++){
        float xv[8];
        #pragma unroll
        for (int cc=0;cc<8;cc++) xv[cc] = lg[cb*8+cc][j];
        #pragma unroll
        for (int oi=0;oi<8;oi++){
            const float* wr = Wp + (size_t)(o0+oi)*NHID + cb*8;
            #pragma unroll
            for (int cc=0;cc<8;cc++) acc[oi] += xv[cc]*wr[cc];
        }
    }
    #pragma unroll
    for (int oi=0;oi<8;oi++){
        y2[((size_t)b*CDIM + o0+oi)*LTOT + l0 + j] = acc[oi];
    }
}

// ------------- K14a: build per-channel 8x8 circular kernel from fft_p -------------
__global__ __launch_bounds__(256) void k_fftker(const float* __restrict__ fp, float* __restrict__ kk){
    int idx = blockIdx.x*256 + threadIdx.x;
    if (idx >= CDIM*64) return;
    int c = idx >> 6, tap = idx & 63;
    int dm = tap >> 3, dn = tap & 7;
    const float R = 0.70710678118654752f;
    const float ct[8] = {1.f, R, 0.f, -R, -1.f, -R, 0.f, R};
    const float* fc = fp + c*40;
    float s = 0.f;
    #pragma unroll
    for (int u=0; u<8; u++){
        #pragma unroll
        for (int v=0; v<8; v++){
            float m1 = (v<=4) ? fc[u*5 + v]
                              : fc[((8-u)&7)*5 + (8-v)];
            int u2 = (8-u)&7, v2 = (8-v)&7;
            float m2 = (v2<=4) ? fc[u2*5 + v2]
                               : fc[((8-u2)&7)*5 + (8-v2)];
            float Ms = 0.5f*(m1+m2);
            s += Ms * ct[(u*dm + v*dn)&7];
        }
    }
    kk[c*64 + dm*8 + dn] = s * (1.0f/64.0f);
}

// ------------- K14b: per-patch circular conv + residual, LDS-staged strips -------------
// Block = one patch-row strip [8][128] of one (b,c) channel. grid = BATCH*CDIM*16.
// Tap weights are wave-uniform -> readfirstlane (SGPR); y-taps come from LDS
// (bank = col%32, 64 distinct cols/wave -> 2-way = free).
__global__ __launch_bounds__(256) void k_patchconv_res(const float* __restrict__ y2,
        const float* __restrict__ kk, float* __restrict__ out){
    __shared__ float ly[8][128];
    __shared__ float lk[64];
    int blk = blockIdx.x;
    int pr = blk & 15;            // patch row (0..15)
    int bc = blk >> 4;            // b*CDIM + c
    int c  = bc & (CDIM-1);
    const float* src = y2 + (size_t)bc*LTOT + pr*8*WDIM;
    float*       dst = out + (size_t)bc*LTOT + pr*8*WDIM;
    int tid = threadIdx.x;
    // stage strip (1024 floats) with 256 float4 loads
    ((float4*)&ly[0][0])[tid] = ((const float4*)src)[tid];
    if (tid < 64) lk[tid] = kk[c*64 + tid];
    __syncthreads();
    // each thread computes 4 outputs: p = q*256 + tid
    float acc0=0.f, acc1=0.f, acc2=0.f, acc3=0.f;
    int h0 = tid >> 7;            // q=0: rows 0..1
    int w0 = tid & 127;
    int wb0 = w0 & ~7, wi0 = w0 & 7;
    #pragma unroll
    for (int dm=0; dm<8; dm++){
        const float* r0 = &ly[(h0  -dm)&7][wb0];
        const float* r1 = &ly[(h0+2-dm)&7][wb0];
        const float* r2 = &ly[(h0+4-dm)&7][wb0];
        const float* r3 = &ly[(h0+6-dm)&7][wb0];
        #pragma unroll
        for (int dn=0; dn<8; dn++){
            float kv = __builtin_amdgcn_readfirstlane(lk[dm*8+dn]);
            int col = (wi0-dn)&7;
            acc0 = fmaf(r0[col], kv, acc0);
            acc1 = fmaf(r1[col], kv, acc1);
            acc2 = fmaf(r2[col], kv, acc2);
            acc3 = fmaf(r3[col], kv, acc3);
        }
    }
    dst[(h0  )*WDIM + w0] += acc0;
    dst[(h0+2)*WDIM + w0] += acc1;
    dst[(h0+4)*WDIM + w0] += acc2;
    dst[(h0+6)*WDIM + w0] += acc3;
}

extern "C" void kernel_launch(void* const* d_in, const int* in_sizes, int n_in,
                              void* d_out, int out_size, void* d_ws, size_t ws_size,
                              hipStream_t stream){
    const float* x         = (const float*)d_in[0];
    const float* norm1_w   = (const float*)d_in[1];
    const float* norm1_b   = (const float*)d_in[2];
    const float* in_proj_w = (const float*)d_in[3];
    const float* conv2d_w  = (const float*)d_in[4];
    const float* conv2d_b  = (const float*)d_in[5];
    const float* x_proj_w  = (const float*)d_in[6];
    const float* x_conv_w  = (const float*)d_in[7];
    const float* x_conv_b  = (const float*)d_in[8];
    const float* dt_projs_w= (const float*)d_in[9];
    const float* dt_projs_b= (const float*)d_in[10];
    const float* A_logs    = (const float*)d_in[11];
    const float* Ds        = (const float*)d_in[12];
    const float* out_norm_w= (const float*)d_in[13];
    const float* out_norm_b= (const float*)d_in[14];
    const float* out_proj_w= (const float*)d_in[15];
    const float* norm2_w   = (const float*)d_in[16];
    const float* norm2_b   = (const float*)d_in[17];
    const float* pin_w     = (const float*)d_in[18];
    const float* dw_w      = (const float*)d_in[19];
    const float* fft_p     = (const float*)d_in[20];
    const float* pout_w    = (const float*)d_in[21];
    float* out = (float*)d_out;
    float* ws  = (float*)d_ws;

    float* xf    = ws + OFF_XF;
    float* z     = ws + OFF_Z;
    float* xin   = ws + OFF_XIN;
    float* xs    = ws + OFF_XS;
    float* xdbl0 = ws + OFF_XDBL0;
    float* xdbl1 = ws + OFF_XDBL1;
    float* y     = ws + OFF_Y;
    float* h2    = ws + OFF_H2;
    float* g     = ws + OFF_G;
    float* y2    = ws + OFF_Y2;
    float* kk    = ws + OFF_KK;

    // ---- SS2D branch ----
    k_flip<<<(BATCH*CDIM*LTOT+255)/256, 256, 0, stream>>>(x, xf);
    k_ln_inproj<<<BATCH*(LTOT/64)*4, 256, 0, stream>>>(xf, norm1_w, norm1_b, in_proj_w, xin, z);
    k_dwconv2d_gelu<<<(BATCH*DINNER*LTOT+255)/256, 256, 0, stream>>>(xin, conv2d_w, conv2d_b, xs);
    k_xproj<<<(BATCH*LTOT+255)/256, 256, 0, stream>>>(xs, x_proj_w, xdbl0);
    k_dwconv1d<<<(BATCH*CDBL*LTOT+255)/256, 256, 0, stream>>>(xdbl0, x_conv_w, x_conv_b, xdbl1);
    k_scan_fused<<<BATCH*DINNER, 1024, 0, stream>>>(xdbl1, xs, A_logs, dt_projs_w, dt_projs_b, Ds, y);
    k_gate_out<<<BATCH*(LTOT/64)*2, 256, 0, stream>>>(y, z, out_norm_w, out_norm_b, out_proj_w, xf, out);

    // ---- EDFFN branch (out currently holds x2) ----
    k_ln_pin<<<BATCH*(LTOT/64)*4, 256, 0, stream>>>(out, norm2_w, norm2_b, pin_w, h2);
    k_dwconv_gate<<<(BATCH*NHID*LTOT+255)/256, 256, 0, stream>>>(h2, dw_w, g);
    k_pout<<<BATCH*(LTOT/64)*2, 256, 0, stream>>>(g, pout_w, y2);
    k_fftker<<<(CDIM*64+255)/256, 256, 0, stream>>>(fft_p, kk);
    k_patchconv_res<<<BATCH*CDIM*16, 256, 0, stream>>>(y2, kk, out);
}